// Round 12
// baseline (376.626 us; speedup 1.0000x reference)
//
#include <hip/hip_runtime.h>
#include <hip/hip_bf16.h>
#include <cstdint>
#include <cstddef>

#define N_NODES 100000
#define N_EDGES 1600000
#define E_TOT   (N_EDGES + N_NODES)
#define F_IN    512
#define HEADS   8
#define HID     8
#define F_H     64          // HEADS*HID
#define NC      40
#define NEG     0.2f

#define BSH    8            // bucket = dst >> 8 (256 nodes/bucket)
#define NB     391          // ceil(100000/256)
#define CHUNKH 8192         // edges per bhist block
#define NBH    ((E_TOT + CHUNKH - 1) / CHUNKH)   // 208
#define CHUNKF 8192         // edges per bfill block (32KB LDS staging)
#define NBF    ((E_TOT + CHUNKF - 1) / CHUNKF)   // 208
#define CAP    7168         // k_cfill LDS staging entries (avg seg ~4350)
#define GEMM_G ((N_NODES + 63) / 64)             // 1563 gemm blocks

typedef __attribute__((ext_vector_type(8))) __bf16 bf16x8;
typedef __attribute__((ext_vector_type(4))) float f32x4;
typedef __attribute__((ext_vector_type(8))) unsigned short u16x8;

__device__ __forceinline__ float bf2f(unsigned short u) {
  unsigned int w = ((unsigned int)u) << 16;
  return __builtin_bit_cast(float, w);
}
__device__ __forceinline__ unsigned short f2bf(float f) {
  __hip_bfloat16 b = __float2bfloat16(f);
  return __builtin_bit_cast(unsigned short, b);
}
__device__ __forceinline__ float lrexp(float v) {
  v = (v > 0.f) ? v : NEG * v;
  return __expf(v);
}

// Per-block edge_index dtype probe: int64 layout -> high int32 words of the
// first 64 entries are all 0. One wave-wide ballot, L2-hot after first block.
__device__ __forceinline__ bool detect_i64(const int* __restrict__ ei) {
  int lane = threadIdx.x & 63;
  int v = ei[2 * lane + 1];
  return __ballot(v != 0) == 0ull;
}

__device__ __forceinline__ int load_dst(const int* __restrict__ ei, bool f, int i) {
  if (i < N_EDGES) return f ? ei[2 * (N_EDGES + i)] : ei[N_EDGES + i];
  return i - N_EDGES;
}
__device__ __forceinline__ int load_src(const int* __restrict__ ei, bool f, int i) {
  if (i < N_EDGES) return f ? ei[2 * i] : ei[i];
  return i - N_EDGES;
}

// ---------------------------------------------------------------------------
// Fat kernel A: blocks [0,16) pack W1 -> bf16 B-fragment-major; blocks
// [16,16+NBH) histogram dst buckets (LDS-binned).
// ---------------------------------------------------------------------------
__global__ __launch_bounds__(256) void k_hist_pack(
    const int* __restrict__ ei, const float* __restrict__ W1,
    uint4* __restrict__ w1f, int* __restrict__ bcnt) {
  __shared__ int h[NB];
  const int t = threadIdx.x;
  if (blockIdx.x < 16) {
    int tid = blockIdx.x * 256 + t;   // 0..4095
    int lane = tid & 63;
    int tt = (tid >> 6) & 3;
    int s = tid >> 8;
    int k0 = s * 32 + ((lane >> 4) << 3);
    int col = tt * 16 + (lane & 15);
    u16x8 v;
#pragma unroll
    for (int i = 0; i < 8; ++i) v[i] = f2bf(W1[(size_t)(k0 + i) * F_H + col]);
    w1f[tid] = __builtin_bit_cast(uint4, v);
    return;
  }
  const int blk = blockIdx.x - 16;
  const bool f = detect_i64(ei);
  for (int i = t; i < NB; i += 256) h[i] = 0;
  __syncthreads();
  const int base = blk * CHUNKH;
#pragma unroll
  for (int j = 0; j < CHUNKH / 256; ++j) {
    int i = base + t + j * 256;
    if (i < E_TOT) atomicAdd(&h[load_dst(ei, f, i) >> BSH], 1);
  }
  __syncthreads();
  for (int i = t; i < NB; i += 256)
    if (h[i]) atomicAdd(&bcnt[i], h[i]);
}

// ---------------------------------------------------------------------------
// Bucket exclusive scan (391 values, one block). Seeds bcur + tails.
// ---------------------------------------------------------------------------
__global__ __launch_bounds__(512) void k_bscan(const int* __restrict__ bcnt,
                                               int* __restrict__ bstart,
                                               int* __restrict__ bcur,
                                               int* __restrict__ rowstart) {
  __shared__ int sh[512];
  const int t = threadIdx.x;
  int v = (t < NB) ? bcnt[t] : 0;
  sh[t] = v;
  __syncthreads();
  for (int d = 1; d < 512; d <<= 1) {
    int u = (t >= d) ? sh[t - d] : 0;
    __syncthreads();
    sh[t] += u;
    __syncthreads();
  }
  if (t < NB) {
    int e = sh[t] - v;
    bstart[t] = e;
    bcur[t] = e;
  }
  if (t == 0) { bstart[NB] = E_TOT; rowstart[N_NODES] = E_TOT; }
}

// ---------------------------------------------------------------------------
// Bin CHUNKF edges in LDS by bucket, flush contiguous per-bucket runs.
// Entry packing: (dst&255)<<24 | src.
// ---------------------------------------------------------------------------
__global__ __launch_bounds__(256) void k_bfill(const int* __restrict__ ei,
                                               int* __restrict__ bcur,
                                               unsigned int* __restrict__ inter) {
  __shared__ unsigned int ent[CHUNKF];                 // 32 KB
  __shared__ int h[NB], ofs[NB], cur[NB], gpos[NB];    // ~6.3 KB
  const int t = threadIdx.x;
  const int base = blockIdx.x * CHUNKF;
  const bool f = detect_i64(ei);
  for (int i = t; i < NB; i += 256) h[i] = 0;
  __syncthreads();
#pragma unroll
  for (int j = 0; j < CHUNKF / 256; ++j) {
    int i = base + t + j * 256;
    if (i < E_TOT) atomicAdd(&h[load_dst(ei, f, i) >> BSH], 1);
  }
  __syncthreads();
  if (t < 64) {
    int loc[7];
    int s = 0;
#pragma unroll
    for (int k = 0; k < 7; ++k) {
      int ix = t * 7 + k;
      int hv = (ix < NB) ? h[ix] : 0;
      loc[k] = s;
      s += hv;
    }
    int incl = s;
    for (int dd = 1; dd < 64; dd <<= 1) {
      int u = __shfl_up(incl, dd);
      if (t >= dd) incl += u;
    }
    int excl = incl - s;
#pragma unroll
    for (int k = 0; k < 7; ++k) {
      int ix = t * 7 + k;
      if (ix < NB) ofs[ix] = excl + loc[k];
    }
  }
  __syncthreads();
  for (int i = t; i < NB; i += 256) {
    cur[i] = ofs[i];
    gpos[i] = h[i] ? atomicAdd(&bcur[i], h[i]) : 0;
  }
  __syncthreads();
#pragma unroll
  for (int j = 0; j < CHUNKF / 256; ++j) {
    int i = base + t + j * 256;
    if (i < E_TOT) {
      int s = load_src(ei, f, i);
      int d = load_dst(ei, f, i);
      int p = atomicAdd(&cur[d >> BSH], 1);
      ent[p] = ((unsigned int)(d & 255) << 24) | (unsigned int)s;
    }
  }
  __syncthreads();
  const int wv = t >> 6, ln = t & 63;
  for (int b = wv; b < NB; b += 4) {
    int c = h[b];
    if (!c) continue;
    int g = gpos[b], o = ofs[b];
    for (int i = ln; i < c; i += 64) inter[g + i] = ent[o + i];
  }
}

// ---------------------------------------------------------------------------
// GEMM1 via MFMA, row-chunk ring staging: chunk = 16 rows x full K (32KB),
// DMA'd as 32 x 1KB FULLY-CONTIGUOUS global_load_lds instructions (the x-read
// pattern of the 6.3TB/s copy ubench). Ring of 2 chunks (64KB -> 2 blocks/CU).
// All 4 waves compute each chunk jointly: wave = 16-col slice, 1 MFMA/k-step.
// LDS linear [16][512] (DMA requires it); ~2x read conflicts hide under fetch.
// Fused logits via oct-level shfl reduce. h1 stored bf16.
// ---------------------------------------------------------------------------
__global__ __launch_bounds__(256) void k_gemm1r(
    const float* __restrict__ x, const uint4* __restrict__ w1f,
    const float* __restrict__ a_src, const float* __restrict__ a_dst,
    unsigned short* __restrict__ h1b, float* __restrict__ als,
    float* __restrict__ ald) {
  __shared__ float xs[2][16 * 512];   // 2 x 32 KB
  const int t = threadIdx.x;
  const int lane = t & 63;
  const int wv = t >> 6;
  const int rb = blockIdx.x * 64;

  // per-lane constants for compute/epilogue
  const int arow = lane & 15;               // A-frag row within chunk
  const int koct = (lane >> 4) << 3;        // A-frag k-offset within k-step
  const int gcol = wv * 16 + (lane & 15);   // output column (D-frag col)
  const float asw = a_src[gcol];
  const float adw = a_dst[gcol];
  const int ghead = (gcol >> 3);            // head of this column
  const int lr0 = (lane >> 4) << 2;         // D-frag row base within chunk

  auto STAGE = [&](int buf, int c) {
#pragma unroll
    for (int j = 0; j < 4; ++j) {
      int r = wv * 4 + j;                   // row within chunk 0..15
      int gr = rb + c * 16 + r;
      if (gr >= N_NODES) gr = N_NODES - 1;
#pragma unroll
      for (int hh = 0; hh < 2; ++hh) {
        const float* src = x + (size_t)gr * F_IN + hh * 256 + lane * 4;
        char* dst = (char*)&xs[buf][r * 512 + hh * 256];
        __builtin_amdgcn_global_load_lds(
            (const __attribute__((address_space(1))) void*)src,
            (__attribute__((address_space(3))) void*)dst, 16, 0, 0);
      }
    }
  };

  STAGE(0, 0);
  int buf = 0;
#pragma unroll
  for (int c = 0; c < 4; ++c) {
    if (c < 3) STAGE(buf ^ 1, c + 1);
    __syncthreads();                        // drains DMA; chunk c data ready
    const float* bufp = xs[buf];

    f32x4 acc = (f32x4){0.f, 0.f, 0.f, 0.f};
#pragma unroll
    for (int sg = 0; sg < 16; ++sg) {
      const float* ap = &bufp[arow * 512 + sg * 32 + koct];
      float4 a0 = *reinterpret_cast<const float4*>(ap);
      float4 a1 = *reinterpret_cast<const float4*>(ap + 4);
      uint4 b = w1f[(sg * 4 + wv) * 64 + lane];
      bf16x8 af;
      af[0] = (__bf16)a0.x; af[1] = (__bf16)a0.y;
      af[2] = (__bf16)a0.z; af[3] = (__bf16)a0.w;
      af[4] = (__bf16)a1.x; af[5] = (__bf16)a1.y;
      af[6] = (__bf16)a1.z; af[7] = (__bf16)a1.w;
      acc = __builtin_amdgcn_mfma_f32_16x16x32_bf16(af, __builtin_bit_cast(bf16x8, b), acc, 0, 0, 0);
    }

    // epilogue for chunk c: rows rb + c*16 + lr0 + i, col gcol
    float sp[4], dp[4];
#pragma unroll
    for (int i = 0; i < 4; ++i) {
      int grow = rb + c * 16 + lr0 + i;
      if (grow < N_NODES) h1b[(size_t)grow * F_H + gcol] = f2bf(acc[i]);
      sp[i] = acc[i] * asw;
      dp[i] = acc[i] * adw;
    }
#pragma unroll
    for (int dd = 1; dd < 8; dd <<= 1)
#pragma unroll
      for (int i = 0; i < 4; ++i) {
        sp[i] += __shfl_xor(sp[i], dd);
        dp[i] += __shfl_xor(dp[i], dd);
      }
    if ((lane & 7) == 0) {
#pragma unroll
      for (int i = 0; i < 4; ++i) {
        int grow = rb + c * 16 + lr0 + i;
        if (grow < N_NODES) {
          als[(size_t)grow * HEADS + ghead] = sp[i];
          ald[(size_t)grow * HEADS + ghead] = dp[i];
        }
      }
    }
    __syncthreads();                        // protect buf before re-stage
    buf ^= 1;
  }
}

// ---------------------------------------------------------------------------
// One block per bucket; LDS counting sort -> csrc + rowstart coalesced.
// ---------------------------------------------------------------------------
__global__ __launch_bounds__(256) void k_cfill(const unsigned int* __restrict__ inter,
                                               const int* __restrict__ bstart,
                                               int* __restrict__ rowstart,
                                               int* __restrict__ csrc) {
  __shared__ unsigned int out_l[CAP];      // 28 KB
  __shared__ int cnt[256], sc[256], cur2[256];
  const int t = threadIdx.x;
  const int b = blockIdx.x;
  const int segStart = bstart[b];
  const int L = bstart[b + 1] - segStart;
  cnt[t] = 0;
  __syncthreads();
  for (int i = t; i < L; i += 256) atomicAdd(&cnt[inter[segStart + i] >> 24], 1);
  __syncthreads();
  sc[t] = cnt[t];
  __syncthreads();
  for (int d = 1; d < 256; d <<= 1) {
    int v = (t >= d) ? sc[t - d] : 0;
    __syncthreads();
    sc[t] += v;
    __syncthreads();
  }
  const int excl = sc[t] - cnt[t];
  cur2[t] = excl;
  const int node = (b << BSH) + t;
  if (node < N_NODES) rowstart[node] = segStart + excl;
  __syncthreads();
  if (L <= CAP) {
    for (int i = t; i < L; i += 256) {
      unsigned int e = inter[segStart + i];
      int p = atomicAdd(&cur2[e >> 24], 1);
      out_l[p] = e & 0xFFFFFFu;
    }
    __syncthreads();
    for (int i = t; i < L; i += 256) csrc[segStart + i] = (int)out_l[i];
  } else {  // safety fallback (statistically never taken)
    for (int i = t; i < L; i += 256) {
      unsigned int e = inter[segStart + i];
      int p = atomicAdd(&cur2[e >> 24], 1);
      csrc[segStart + p] = (int)(e & 0xFFFFFFu);
    }
  }
}

// ---------------------------------------------------------------------------
// Layer-1 aggregation: wave = 8 nodes x 8 lanes. Lane = head = 8 features
// (one dwordx4 of bf16 per edge). Unroll x4 -> 32 gathers in flight per wave.
// ---------------------------------------------------------------------------
__global__ __launch_bounds__(256) void k_agg1n(
    const int* __restrict__ rowstart, const int* __restrict__ csrc,
    const unsigned short* __restrict__ h1b, const float* __restrict__ als,
    const float* __restrict__ ald, const float* __restrict__ b1,
    unsigned short* __restrict__ hactb) {
  const int w = (int)((blockIdx.x * 256 + threadIdx.x) >> 6);
  const int lane = threadIdx.x & 63;
  const int grp = lane >> 3;        // node slot 0..7
  const int l = lane & 7;           // head / feature octet
  const int n = w * 8 + grp;
  const bool live = (n < N_NODES);
  const int e0 = live ? rowstart[n] : 0;
  const int e1 = live ? rowstart[n + 1] : 0;
  const float aldv = live ? ald[(size_t)n * HEADS + l] : 0.f;

  float den = 0.f;
  float acc[8];
#pragma unroll
  for (int k = 0; k < 8; ++k) acc[k] = 0.f;

  int e = e0;
  for (; e + 4 <= e1; e += 4) {
    int4 sv = *reinterpret_cast<const int4*>(&csrc[e]);
    float a0 = als[(size_t)sv.x * HEADS + l];
    float a1 = als[(size_t)sv.y * HEADS + l];
    float a2 = als[(size_t)sv.z * HEADS + l];
    float a3 = als[(size_t)sv.w * HEADS + l];
    uint4 u0 = *reinterpret_cast<const uint4*>(&h1b[(size_t)sv.x * F_H + l * 8]);
    uint4 u1 = *reinterpret_cast<const uint4*>(&h1b[(size_t)sv.y * F_H + l * 8]);
    uint4 u2 = *reinterpret_cast<const uint4*>(&h1b[(size_t)sv.z * F_H + l * 8]);
    uint4 u3 = *reinterpret_cast<const uint4*>(&h1b[(size_t)sv.w * F_H + l * 8]);
    float p0 = lrexp(a0 + aldv), p1 = lrexp(a1 + aldv);
    float p2 = lrexp(a2 + aldv), p3 = lrexp(a3 + aldv);
    den += (p0 + p1) + (p2 + p3);
    const unsigned int* q0 = &u0.x;
    const unsigned int* q1 = &u1.x;
    const unsigned int* q2 = &u2.x;
    const unsigned int* q3 = &u3.x;
#pragma unroll
    for (int k = 0; k < 4; ++k) {
      acc[2 * k]     += p0 * bf2f((unsigned short)q0[k]) + p1 * bf2f((unsigned short)q1[k])
                      + p2 * bf2f((unsigned short)q2[k]) + p3 * bf2f((unsigned short)q3[k]);
      acc[2 * k + 1] += p0 * bf2f((unsigned short)(q0[k] >> 16)) + p1 * bf2f((unsigned short)(q1[k] >> 16))
                      + p2 * bf2f((unsigned short)(q2[k] >> 16)) + p3 * bf2f((unsigned short)(q3[k] >> 16));
    }
  }
  for (; e < e1; ++e) {
    int s = csrc[e];
    float a = als[(size_t)s * HEADS + l];
    uint4 u = *reinterpret_cast<const uint4*>(&h1b[(size_t)s * F_H + l * 8]);
    float p = lrexp(a + aldv);
    den += p;
    const unsigned int* q = &u.x;
#pragma unroll
    for (int k = 0; k < 4; ++k) {
      acc[2 * k]     += p * bf2f((unsigned short)q[k]);
      acc[2 * k + 1] += p * bf2f((unsigned short)(q[k] >> 16));
    }
  }

  if (live) {
    float inv = 1.f / den;
    uint4 outw;
    unsigned int* ow = &outw.x;
#pragma unroll
    for (int k = 0; k < 4; ++k) {
      float ox = acc[2 * k] * inv + b1[l * 8 + 2 * k];
      float oy = acc[2 * k + 1] * inv + b1[l * 8 + 2 * k + 1];
      ox = (ox > 0.f) ? ox : expm1f(ox);
      oy = (oy > 0.f) ? oy : expm1f(oy);
      ow[k] = ((unsigned int)f2bf(oy) << 16) | (unsigned int)f2bf(ox);
    }
    *reinterpret_cast<uint4*>(&hactb[(size_t)n * F_H + l * 8]) = outw;
  }
}

// ---------------------------------------------------------------------------
// Layer-2 projection: h2 = hact @ W2 (64x40) + attention logits (1 head).
// ---------------------------------------------------------------------------
__global__ __launch_bounds__(256) void k_l2proj(
    const unsigned short* __restrict__ hactb, const float* __restrict__ W2,
    const float* __restrict__ a_src2, const float* __restrict__ a_dst2,
    unsigned short* __restrict__ h2b, float* __restrict__ als2,
    float* __restrict__ ald2) {
  __shared__ float hs[64 * 68];
  __shared__ float w2s[F_H * NC];
  const int t = threadIdx.x;
  const int nb = blockIdx.x * 64;
  {
    int r0 = t >> 3, c8 = t & 7;
#pragma unroll
    for (int i = 0; i < 2; ++i) {
      int r = r0 + i * 32;
      int gr = nb + r;
      u16x8 v = (u16x8)(0);
      if (gr < N_NODES)
        v = *reinterpret_cast<const u16x8*>(&hactb[(size_t)gr * F_H + c8 * 8]);
#pragma unroll
      for (int k = 0; k < 8; ++k) hs[r * 68 + c8 * 8 + k] = bf2f(v[k]);
    }
  }
  for (int i = t; i < F_H * NC; i += 256) w2s[i] = W2[i];
  __syncthreads();

  const int node = t >> 2, cg = t & 3;
  float acc[10];
#pragma unroll
  for (int c = 0; c < 10; ++c) acc[c] = 0.f;
  for (int k = 0; k < F_H; ++k) {
    float xv = hs[node * 68 + k];
#pragma unroll
    for (int c = 0; c < 10; ++c) acc[c] += xv * w2s[k * NC + cg * 10 + c];
  }
  const int gn = nb + node;
  float ps = 0.f, pd = 0.f;
#pragma unroll
  for (int c = 0; c < 10; ++c) {
    ps += acc[c] * a_src2[cg * 10 + c];
    pd += acc[c] * a_dst2[cg * 10 + c];
  }
  ps += __shfl_xor(ps, 1); ps += __shfl_xor(ps, 2);
  pd += __shfl_xor(pd, 1); pd += __shfl_xor(pd, 2);
  if (gn < N_NODES) {
#pragma unroll
    for (int c = 0; c < 10; ++c) h2b[(size_t)gn * NC + cg * 10 + c] = f2bf(acc[c]);
    if (cg == 0) { als2[gn] = ps; ald2[gn] = pd; }
  }
}

// ---------------------------------------------------------------------------
// Layer-2 aggregation + bias + log_softmax. Wave = 8 nodes x 8 lanes;
// lanes l<5 each carry 8 classes (one dwordx4 bf16 gather). Unroll x4.
// ---------------------------------------------------------------------------
__global__ __launch_bounds__(256) void k_agg2n(
    const int* __restrict__ rowstart, const int* __restrict__ csrc,
    const unsigned short* __restrict__ h2b, const float* __restrict__ als2,
    const float* __restrict__ ald2, const float* __restrict__ b2,
    float* __restrict__ out) {
  const int w = (int)((blockIdx.x * 256 + threadIdx.x) >> 6);
  const int lane = threadIdx.x & 63;
  const int grp = lane >> 3;
  const int l = lane & 7;
  const int n = w * 8 + grp;
  const bool live = (n < N_NODES);
  const int e0 = live ? rowstart[n] : 0;
  const int e1 = live ? rowstart[n + 1] : 0;
  const float aldv = live ? ald2[n] : 0.f;
  const bool act = (l < 5);
  const int fo = act ? l * 8 : 0;

  float den = 0.f;
  float acc[8];
#pragma unroll
  for (int k = 0; k < 8; ++k) acc[k] = 0.f;

  int e = e0;
  for (; e + 4 <= e1; e += 4) {
    int4 sv = *reinterpret_cast<const int4*>(&csrc[e]);
    float a0 = als2[sv.x], a1 = als2[sv.y], a2 = als2[sv.z], a3 = als2[sv.w];
    uint4 u0 = *reinterpret_cast<const uint4*>(&h2b[(size_t)sv.x * NC + fo]);
    uint4 u1 = *reinterpret_cast<const uint4*>(&h2b[(size_t)sv.y * NC + fo]);
    uint4 u2 = *reinterpret_cast<const uint4*>(&h2b[(size_t)sv.z * NC + fo]);
    uint4 u3 = *reinterpret_cast<const uint4*>(&h2b[(size_t)sv.w * NC + fo]);
    float p0 = lrexp(a0 + aldv), p1 = lrexp(a1 + aldv);
    float p2 = lrexp(a2 + aldv), p3 = lrexp(a3 + aldv);
    den += (p0 + p1) + (p2 + p3);
    const unsigned int* q0 = &u0.x;
    const unsigned int* q1 = &u1.x;
    const unsigned int* q2 = &u2.x;
    const unsigned int* q3 = &u3.x;
#pragma unroll
    for (int k = 0; k < 4; ++k) {
      acc[2 * k]     += p0 * bf2f((unsigned short)q0[k]) + p1 * bf2f((unsigned short)q1[k])
                      + p2 * bf2f((unsigned short)q2[k]) + p3 * bf2f((unsigned short)q3[k]);
      acc[2 * k + 1] += p0 * bf2f((unsigned short)(q0[k] >> 16)) + p1 * bf2f((unsigned short)(q1[k] >> 16))
                      + p2 * bf2f((unsigned short)(q2[k] >> 16)) + p3 * bf2f((unsigned short)(q3[k] >> 16));
    }
  }
  for (; e < e1; ++e) {
    int s = csrc[e];
    float a = als2[s];
    uint4 u = *reinterpret_cast<const uint4*>(&h2b[(size_t)s * NC + fo]);
    float p = lrexp(a + aldv);
    den += p;
    const unsigned int* q = &u.x;
#pragma unroll
    for (int k = 0; k < 4; ++k) {
      acc[2 * k]     += p * bf2f((unsigned short)q[k]);
      acc[2 * k + 1] += p * bf2f((unsigned short)(q[k] >> 16));
    }
  }

  float o[8];
  float inv = 1.f / den;
  float mx = -1e30f;
#pragma unroll
  for (int k = 0; k < 8; ++k) {
    o[k] = act ? (acc[k] * inv + b2[fo + k]) : -1e30f;
    mx = fmaxf(mx, o[k]);
  }
  mx = fmaxf(mx, __shfl_xor(mx, 1));
  mx = fmaxf(mx, __shfl_xor(mx, 2));
  mx = fmaxf(mx, __shfl_xor(mx, 4));
  float se = 0.f;
#pragma unroll
  for (int k = 0; k < 8; ++k) se += act ? __expf(o[k] - mx) : 0.f;
  se += __shfl_xor(se, 1);
  se += __shfl_xor(se, 2);
  se += __shfl_xor(se, 4);
  if (live && act) {
    float ls = __logf(se);
    float4 r0, r1;
    r0.x = o[0] - mx - ls; r0.y = o[1] - mx - ls;
    r0.z = o[2] - mx - ls; r0.w = o[3] - mx - ls;
    r1.x = o[4] - mx - ls; r1.y = o[5] - mx - ls;
    r1.z = o[6] - mx - ls; r1.w = o[7] - mx - ls;
    *reinterpret_cast<float4*>(&out[(size_t)n * NC + l * 8]) = r0;
    *reinterpret_cast<float4*>(&out[(size_t)n * NC + l * 8 + 4]) = r1;
  }
}

// ---------------------------------------------------------------------------
extern "C" void kernel_launch(void* const* d_in, const int* in_sizes, int n_in,
                              void* d_out, int out_size, void* d_ws, size_t ws_size,
                              hipStream_t stream) {
  const float* x      = (const float*)d_in[0];
  const int*   ei     = (const int*)d_in[1];
  const float* W1     = (const float*)d_in[2];
  const float* a_src1 = (const float*)d_in[3];
  const float* a_dst1 = (const float*)d_in[4];
  const float* b1     = (const float*)d_in[5];
  const float* W2     = (const float*)d_in[6];
  const float* a_src2 = (const float*)d_in[7];
  const float* a_dst2 = (const float*)d_in[8];
  const float* b2     = (const float*)d_in[9];
  float* out = (float*)d_out;

  char* ws = (char*)d_ws;
  size_t o = 0;
  auto carve = [&](size_t bytes) -> char* {
    char* p = ws + o;
    o = (o + bytes + 255) & ~(size_t)255;
    return p;
  };
  int*   bcnt     = (int*)carve((size_t)NB * 4);
  int*   bstart   = (int*)carve((size_t)(NB + 1) * 4);
  int*   bcur     = (int*)carve((size_t)NB * 4);
  int*   rowstart = (int*)carve((size_t)(N_NODES + 1) * 4);
  unsigned int* inter = (unsigned int*)carve((size_t)E_TOT * 4);
  int*   csrc     = (int*)carve((size_t)(E_TOT + 8) * 4);   // +pad for int4 tail read
  uint4* w1f      = (uint4*)carve((size_t)4096 * 16);
  unsigned short* h1b   = (unsigned short*)carve((size_t)N_NODES * F_H * 2);
  float* als1     = (float*)carve((size_t)N_NODES * HEADS * 4);
  float* ald1     = (float*)carve((size_t)N_NODES * HEADS * 4);
  unsigned short* hactb = (unsigned short*)carve((size_t)N_NODES * F_H * 2);
  unsigned short* h2b   = (unsigned short*)carve((size_t)(N_NODES * NC + 8) * 2);
  float* als2     = (float*)carve((size_t)N_NODES * 4);
  float* ald2     = (float*)carve((size_t)N_NODES * 4);
  (void)ws_size; (void)n_in; (void)in_sizes; (void)out_size;

  hipMemsetAsync(bcnt, 0, (size_t)NB * 4, stream);
  k_hist_pack<<<16 + NBH, 256, 0, stream>>>(ei, W1, w1f, bcnt);
  k_bscan<<<1, 512, 0, stream>>>(bcnt, bstart, bcur, rowstart);
  k_bfill<<<NBF, 256, 0, stream>>>(ei, bcur, inter);
  k_gemm1r<<<GEMM_G, 256, 0, stream>>>(x, w1f, a_src1, a_dst1, h1b, als1, ald1);
  k_cfill<<<NB, 256, 0, stream>>>(inter, bstart, rowstart, csrc);

  const int aggGrid = (N_NODES + 31) / 32;   // 8 nodes/wave, 4 waves/block
  k_agg1n<<<aggGrid, 256, 0, stream>>>(rowstart, csrc, h1b, als1, ald1, b1, hactb);
  k_l2proj<<<(N_NODES + 63) / 64, 256, 0, stream>>>(hactb, W2, a_src2, a_dst2, h2b, als2, ald2);
  k_agg2n<<<aggGrid, 256, 0, stream>>>(rowstart, csrc, h2b, als2, ald2, b2, out);
}

// Round 13
// 265.458 us; speedup vs baseline: 1.4188x; 1.4188x over previous
//
#include <hip/hip_runtime.h>
#include <hip/hip_bf16.h>
#include <cstdint>
#include <cstddef>

#define N_NODES 100000
#define N_EDGES 1600000
#define E_TOT   (N_EDGES + N_NODES)
#define F_IN    512
#define HEADS   8
#define HID     8
#define F_H     64          // HEADS*HID
#define NC      40
#define NEG     0.2f

#define BSH    8            // bucket = dst >> 8 (256 nodes/bucket)
#define NB     391          // ceil(100000/256)
#define CHUNKH 8192         // edges per bhist block
#define NBH    ((E_TOT + CHUNKH - 1) / CHUNKH)   // 208
#define CHUNKF 8192         // edges per bfill block (32KB LDS staging)
#define NBF    ((E_TOT + CHUNKF - 1) / CHUNKF)   // 208
#define CAP    7168         // k_cfill LDS staging entries (avg seg ~4350)
#define GEMM_G ((N_NODES + 63) / 64)             // 1563 gemm blocks

typedef __attribute__((ext_vector_type(8))) __bf16 bf16x8;
typedef __attribute__((ext_vector_type(4))) float f32x4;
typedef __attribute__((ext_vector_type(8))) unsigned short u16x8;

__device__ __forceinline__ float bf2f(unsigned short u) {
  unsigned int w = ((unsigned int)u) << 16;
  return __builtin_bit_cast(float, w);
}
__device__ __forceinline__ unsigned short f2bf(float f) {
  __hip_bfloat16 b = __float2bfloat16(f);
  return __builtin_bit_cast(unsigned short, b);
}
__device__ __forceinline__ float lrexp(float v) {
  v = (v > 0.f) ? v : NEG * v;
  return __expf(v);
}

// Per-block edge_index dtype probe: int64 layout -> high int32 words of the
// first 64 entries are all 0. One wave-wide ballot, L2-hot after first block.
__device__ __forceinline__ bool detect_i64(const int* __restrict__ ei) {
  int lane = threadIdx.x & 63;
  int v = ei[2 * lane + 1];
  return __ballot(v != 0) == 0ull;
}

__device__ __forceinline__ int load_dst(const int* __restrict__ ei, bool f, int i) {
  if (i < N_EDGES) return f ? ei[2 * (N_EDGES + i)] : ei[N_EDGES + i];
  return i - N_EDGES;
}
__device__ __forceinline__ int load_src(const int* __restrict__ ei, bool f, int i) {
  if (i < N_EDGES) return f ? ei[2 * i] : ei[i];
  return i - N_EDGES;
}

// ---------------------------------------------------------------------------
// Fat kernel A: blocks [0,16) pack W1 -> bf16 B-fragment-major; blocks
// [16,16+NBH) histogram dst buckets (LDS-binned).
// ---------------------------------------------------------------------------
__global__ __launch_bounds__(256) void k_hist_pack(
    const int* __restrict__ ei, const float* __restrict__ W1,
    uint4* __restrict__ w1f, int* __restrict__ bcnt) {
  __shared__ int h[NB];
  const int t = threadIdx.x;
  if (blockIdx.x < 16) {
    int tid = blockIdx.x * 256 + t;   // 0..4095
    int lane = tid & 63;
    int tt = (tid >> 6) & 3;
    int s = tid >> 8;
    int k0 = s * 32 + ((lane >> 4) << 3);
    int col = tt * 16 + (lane & 15);
    u16x8 v;
#pragma unroll
    for (int i = 0; i < 8; ++i) v[i] = f2bf(W1[(size_t)(k0 + i) * F_H + col]);
    w1f[tid] = __builtin_bit_cast(uint4, v);
    return;
  }
  const int blk = blockIdx.x - 16;
  const bool f = detect_i64(ei);
  for (int i = t; i < NB; i += 256) h[i] = 0;
  __syncthreads();
  const int base = blk * CHUNKH;
#pragma unroll
  for (int j = 0; j < CHUNKH / 256; ++j) {
    int i = base + t + j * 256;
    if (i < E_TOT) atomicAdd(&h[load_dst(ei, f, i) >> BSH], 1);
  }
  __syncthreads();
  for (int i = t; i < NB; i += 256)
    if (h[i]) atomicAdd(&bcnt[i], h[i]);
}

// ---------------------------------------------------------------------------
// Bucket exclusive scan (391 values, one block). Seeds bcur + tails.
// ---------------------------------------------------------------------------
__global__ __launch_bounds__(512) void k_bscan(const int* __restrict__ bcnt,
                                               int* __restrict__ bstart,
                                               int* __restrict__ bcur,
                                               int* __restrict__ rowstart) {
  __shared__ int sh[512];
  const int t = threadIdx.x;
  int v = (t < NB) ? bcnt[t] : 0;
  sh[t] = v;
  __syncthreads();
  for (int d = 1; d < 512; d <<= 1) {
    int u = (t >= d) ? sh[t - d] : 0;
    __syncthreads();
    sh[t] += u;
    __syncthreads();
  }
  if (t < NB) {
    int e = sh[t] - v;
    bstart[t] = e;
    bcur[t] = e;
  }
  if (t == 0) { bstart[NB] = E_TOT; rowstart[N_NODES] = E_TOT; }
}

// ---------------------------------------------------------------------------
// Bin CHUNKF edges in LDS by bucket, flush contiguous per-bucket runs.
// Entry packing: (dst&255)<<24 | src.
// ---------------------------------------------------------------------------
__global__ __launch_bounds__(256) void k_bfill(const int* __restrict__ ei,
                                               int* __restrict__ bcur,
                                               unsigned int* __restrict__ inter) {
  __shared__ unsigned int ent[CHUNKF];                 // 32 KB
  __shared__ int h[NB], ofs[NB], cur[NB], gpos[NB];    // ~6.3 KB
  const int t = threadIdx.x;
  const int base = blockIdx.x * CHUNKF;
  const bool f = detect_i64(ei);
  for (int i = t; i < NB; i += 256) h[i] = 0;
  __syncthreads();
#pragma unroll
  for (int j = 0; j < CHUNKF / 256; ++j) {
    int i = base + t + j * 256;
    if (i < E_TOT) atomicAdd(&h[load_dst(ei, f, i) >> BSH], 1);
  }
  __syncthreads();
  if (t < 64) {
    int loc[7];
    int s = 0;
#pragma unroll
    for (int k = 0; k < 7; ++k) {
      int ix = t * 7 + k;
      int hv = (ix < NB) ? h[ix] : 0;
      loc[k] = s;
      s += hv;
    }
    int incl = s;
    for (int dd = 1; dd < 64; dd <<= 1) {
      int u = __shfl_up(incl, dd);
      if (t >= dd) incl += u;
    }
    int excl = incl - s;
#pragma unroll
    for (int k = 0; k < 7; ++k) {
      int ix = t * 7 + k;
      if (ix < NB) ofs[ix] = excl + loc[k];
    }
  }
  __syncthreads();
  for (int i = t; i < NB; i += 256) {
    cur[i] = ofs[i];
    gpos[i] = h[i] ? atomicAdd(&bcur[i], h[i]) : 0;
  }
  __syncthreads();
#pragma unroll
  for (int j = 0; j < CHUNKF / 256; ++j) {
    int i = base + t + j * 256;
    if (i < E_TOT) {
      int s = load_src(ei, f, i);
      int d = load_dst(ei, f, i);
      int p = atomicAdd(&cur[d >> BSH], 1);
      ent[p] = ((unsigned int)(d & 255) << 24) | (unsigned int)s;
    }
  }
  __syncthreads();
  const int wv = t >> 6, ln = t & 63;
  for (int b = wv; b < NB; b += 4) {
    int c = h[b];
    if (!c) continue;
    int g = gpos[b], o = ofs[b];
    for (int i = ln; i < c; i += 64) inter[g + i] = ent[o + i];
  }
}

// ---------------------------------------------------------------------------
// GEMM1 via MFMA, row-chunk ring staging. Chunk = 16 rows x full K (32KB),
// DMA'd as 32 x 1KB-span global_load_lds instructions. FIXES vs R12:
//  (1) rule-#21 both-sides XOR swizzle: global source slot = lane ^ (r&7)
//      within each 1KB span (lanes permuted inside 128B groups, span still
//      contiguous); ds_read applies the same XOR -> each bank-quad hit
//      exactly 8x/wave = the b128 floor (conflict-free).
//  (2) m97 barrier order: STAGE(next) -> compute(cur) -> barrier, so the
//      DMA is in flight ACROSS compute instead of drained before it.
// Wave = 16-col slice; 1 MFMA/k-step; fused logits epilogue; h1 bf16.
// ---------------------------------------------------------------------------
__global__ __launch_bounds__(256) void k_gemm1r(
    const float* __restrict__ x, const uint4* __restrict__ w1f,
    const float* __restrict__ a_src, const float* __restrict__ a_dst,
    unsigned short* __restrict__ h1b, float* __restrict__ als,
    float* __restrict__ ald) {
  __shared__ float xs[2][16 * 512];   // 2 x 32 KB
  const int t = threadIdx.x;
  const int lane = t & 63;
  const int wv = t >> 6;
  const int rb = blockIdx.x * 64;

  const int arow = lane & 15;               // A-frag row within chunk
  const int a7 = arow & 7;
  const int gsl = (lane >> 4) << 1;         // 16B-slot pair base within k-step
  const int gcol = wv * 16 + (lane & 15);   // output column (D-frag col)
  const float asw = a_src[gcol];
  const float adw = a_dst[gcol];
  const int ghead = (gcol >> 3);
  const int lr0 = (lane >> 4) << 2;         // D-frag row base within chunk

  auto STAGE = [&](int buf, int c) {
#pragma unroll
    for (int j = 0; j < 4; ++j) {
      int r = wv * 4 + j;                   // row within chunk 0..15
      int gr = rb + c * 16 + r;
      if (gr >= N_NODES) gr = N_NODES - 1;
#pragma unroll
      for (int hh = 0; hh < 2; ++hh) {
        // pre-swizzled source: lane's 16B comes from slot (lane ^ r&7)
        const float* src = x + (size_t)gr * F_IN + hh * 256 + ((lane ^ (r & 7)) << 2);
        char* dst = (char*)&xs[buf][r * 512 + hh * 256];
        __builtin_amdgcn_global_load_lds(
            (const __attribute__((address_space(1))) void*)src,
            (__attribute__((address_space(3))) void*)dst, 16, 0, 0);
      }
    }
  };

  STAGE(0, 0);
  __syncthreads();                          // chunk 0 resident
  int buf = 0;
#pragma unroll
  for (int c = 0; c < 4; ++c) {
    if (c < 3) STAGE(buf ^ 1, c + 1);       // prefetch in flight across compute
    const float* bufp = xs[buf];

    f32x4 acc = (f32x4){0.f, 0.f, 0.f, 0.f};
#pragma unroll
    for (int sg = 0; sg < 16; ++sg) {
      int g0 = sg * 8 + gsl;
      const float* ap = &bufp[arow * 512];
      float4 a0 = *reinterpret_cast<const float4*>(ap + ((g0 ^ a7) << 2));
      float4 a1 = *reinterpret_cast<const float4*>(ap + (((g0 + 1) ^ a7) << 2));
      uint4 b = w1f[(sg * 4 + wv) * 64 + lane];
      bf16x8 af;
      af[0] = (__bf16)a0.x; af[1] = (__bf16)a0.y;
      af[2] = (__bf16)a0.z; af[3] = (__bf16)a0.w;
      af[4] = (__bf16)a1.x; af[5] = (__bf16)a1.y;
      af[6] = (__bf16)a1.z; af[7] = (__bf16)a1.w;
      acc = __builtin_amdgcn_mfma_f32_16x16x32_bf16(af, __builtin_bit_cast(bf16x8, b), acc, 0, 0, 0);
    }

    // epilogue for chunk c: rows rb + c*16 + lr0 + i, col gcol
    float sp[4], dp[4];
#pragma unroll
    for (int i = 0; i < 4; ++i) {
      int grow = rb + c * 16 + lr0 + i;
      if (grow < N_NODES) h1b[(size_t)grow * F_H + gcol] = f2bf(acc[i]);
      sp[i] = acc[i] * asw;
      dp[i] = acc[i] * adw;
    }
#pragma unroll
    for (int dd = 1; dd < 8; dd <<= 1)
#pragma unroll
      for (int i = 0; i < 4; ++i) {
        sp[i] += __shfl_xor(sp[i], dd);
        dp[i] += __shfl_xor(dp[i], dd);
      }
    if ((lane & 7) == 0) {
#pragma unroll
      for (int i = 0; i < 4; ++i) {
        int grow = rb + c * 16 + lr0 + i;
        if (grow < N_NODES) {
          als[(size_t)grow * HEADS + ghead] = sp[i];
          ald[(size_t)grow * HEADS + ghead] = dp[i];
        }
      }
    }
    __syncthreads();                        // drains prefetch; next buf ready
    buf ^= 1;
  }
}

// ---------------------------------------------------------------------------
// One block per bucket; LDS counting sort -> csrc + rowstart coalesced.
// ---------------------------------------------------------------------------
__global__ __launch_bounds__(256) void k_cfill(const unsigned int* __restrict__ inter,
                                               const int* __restrict__ bstart,
                                               int* __restrict__ rowstart,
                                               int* __restrict__ csrc) {
  __shared__ unsigned int out_l[CAP];      // 28 KB
  __shared__ int cnt[256], sc[256], cur2[256];
  const int t = threadIdx.x;
  const int b = blockIdx.x;
  const int segStart = bstart[b];
  const int L = bstart[b + 1] - segStart;
  cnt[t] = 0;
  __syncthreads();
  for (int i = t; i < L; i += 256) atomicAdd(&cnt[inter[segStart + i] >> 24], 1);
  __syncthreads();
  sc[t] = cnt[t];
  __syncthreads();
  for (int d = 1; d < 256; d <<= 1) {
    int v = (t >= d) ? sc[t - d] : 0;
    __syncthreads();
    sc[t] += v;
    __syncthreads();
  }
  const int excl = sc[t] - cnt[t];
  cur2[t] = excl;
  const int node = (b << BSH) + t;
  if (node < N_NODES) rowstart[node] = segStart + excl;
  __syncthreads();
  if (L <= CAP) {
    for (int i = t; i < L; i += 256) {
      unsigned int e = inter[segStart + i];
      int p = atomicAdd(&cur2[e >> 24], 1);
      out_l[p] = e & 0xFFFFFFu;
    }
    __syncthreads();
    for (int i = t; i < L; i += 256) csrc[segStart + i] = (int)out_l[i];
  } else {  // safety fallback (statistically never taken)
    for (int i = t; i < L; i += 256) {
      unsigned int e = inter[segStart + i];
      int p = atomicAdd(&cur2[e >> 24], 1);
      csrc[segStart + p] = (int)(e & 0xFFFFFFu);
    }
  }
}

// ---------------------------------------------------------------------------
// Layer-1 aggregation: wave = 8 nodes x 8 lanes. Lane = head = 8 features
// (one dwordx4 of bf16 per edge). Unroll x4 -> 32 gathers in flight per wave.
// ---------------------------------------------------------------------------
__global__ __launch_bounds__(256) void k_agg1n(
    const int* __restrict__ rowstart, const int* __restrict__ csrc,
    const unsigned short* __restrict__ h1b, const float* __restrict__ als,
    const float* __restrict__ ald, const float* __restrict__ b1,
    unsigned short* __restrict__ hactb) {
  const int w = (int)((blockIdx.x * 256 + threadIdx.x) >> 6);
  const int lane = threadIdx.x & 63;
  const int grp = lane >> 3;        // node slot 0..7
  const int l = lane & 7;           // head / feature octet
  const int n = w * 8 + grp;
  const bool live = (n < N_NODES);
  const int e0 = live ? rowstart[n] : 0;
  const int e1 = live ? rowstart[n + 1] : 0;
  const float aldv = live ? ald[(size_t)n * HEADS + l] : 0.f;

  float den = 0.f;
  float acc[8];
#pragma unroll
  for (int k = 0; k < 8; ++k) acc[k] = 0.f;

  int e = e0;
  for (; e + 4 <= e1; e += 4) {
    int4 sv = *reinterpret_cast<const int4*>(&csrc[e]);
    float a0 = als[(size_t)sv.x * HEADS + l];
    float a1 = als[(size_t)sv.y * HEADS + l];
    float a2 = als[(size_t)sv.z * HEADS + l];
    float a3 = als[(size_t)sv.w * HEADS + l];
    uint4 u0 = *reinterpret_cast<const uint4*>(&h1b[(size_t)sv.x * F_H + l * 8]);
    uint4 u1 = *reinterpret_cast<const uint4*>(&h1b[(size_t)sv.y * F_H + l * 8]);
    uint4 u2 = *reinterpret_cast<const uint4*>(&h1b[(size_t)sv.z * F_H + l * 8]);
    uint4 u3 = *reinterpret_cast<const uint4*>(&h1b[(size_t)sv.w * F_H + l * 8]);
    float p0 = lrexp(a0 + aldv), p1 = lrexp(a1 + aldv);
    float p2 = lrexp(a2 + aldv), p3 = lrexp(a3 + aldv);
    den += (p0 + p1) + (p2 + p3);
    const unsigned int* q0 = &u0.x;
    const unsigned int* q1 = &u1.x;
    const unsigned int* q2 = &u2.x;
    const unsigned int* q3 = &u3.x;
#pragma unroll
    for (int k = 0; k < 4; ++k) {
      acc[2 * k]     += p0 * bf2f((unsigned short)q0[k]) + p1 * bf2f((unsigned short)q1[k])
                      + p2 * bf2f((unsigned short)q2[k]) + p3 * bf2f((unsigned short)q3[k]);
      acc[2 * k + 1] += p0 * bf2f((unsigned short)(q0[k] >> 16)) + p1 * bf2f((unsigned short)(q1[k] >> 16))
                      + p2 * bf2f((unsigned short)(q2[k] >> 16)) + p3 * bf2f((unsigned short)(q3[k] >> 16));
    }
  }
  for (; e < e1; ++e) {
    int s = csrc[e];
    float a = als[(size_t)s * HEADS + l];
    uint4 u = *reinterpret_cast<const uint4*>(&h1b[(size_t)s * F_H + l * 8]);
    float p = lrexp(a + aldv);
    den += p;
    const unsigned int* q = &u.x;
#pragma unroll
    for (int k = 0; k < 4; ++k) {
      acc[2 * k]     += p * bf2f((unsigned short)q[k]);
      acc[2 * k + 1] += p * bf2f((unsigned short)(q[k] >> 16));
    }
  }

  if (live) {
    float inv = 1.f / den;
    uint4 outw;
    unsigned int* ow = &outw.x;
#pragma unroll
    for (int k = 0; k < 4; ++k) {
      float ox = acc[2 * k] * inv + b1[l * 8 + 2 * k];
      float oy = acc[2 * k + 1] * inv + b1[l * 8 + 2 * k + 1];
      ox = (ox > 0.f) ? ox : expm1f(ox);
      oy = (oy > 0.f) ? oy : expm1f(oy);
      ow[k] = ((unsigned int)f2bf(oy) << 16) | (unsigned int)f2bf(ox);
    }
    *reinterpret_cast<uint4*>(&hactb[(size_t)n * F_H + l * 8]) = outw;
  }
}

// ---------------------------------------------------------------------------
// Layer-2 projection: h2 = hact @ W2 (64x40) + attention logits (1 head).
// ---------------------------------------------------------------------------
__global__ __launch_bounds__(256) void k_l2proj(
    const unsigned short* __restrict__ hactb, const float* __restrict__ W2,
    const float* __restrict__ a_src2, const float* __restrict__ a_dst2,
    unsigned short* __restrict__ h2b, float* __restrict__ als2,
    float* __restrict__ ald2) {
  __shared__ float hs[64 * 68];
  __shared__ float w2s[F_H * NC];
  const int t = threadIdx.x;
  const int nb = blockIdx.x * 64;
  {
    int r0 = t >> 3, c8 = t & 7;
#pragma unroll
    for (int i = 0; i < 2; ++i) {
      int r = r0 + i * 32;
      int gr = nb + r;
      u16x8 v = (u16x8)(0);
      if (gr < N_NODES)
        v = *reinterpret_cast<const u16x8*>(&hactb[(size_t)gr * F_H + c8 * 8]);
#pragma unroll
      for (int k = 0; k < 8; ++k) hs[r * 68 + c8 * 8 + k] = bf2f(v[k]);
    }
  }
  for (int i = t; i < F_H * NC; i += 256) w2s[i] = W2[i];
  __syncthreads();

  const int node = t >> 2, cg = t & 3;
  float acc[10];
#pragma unroll
  for (int c = 0; c < 10; ++c) acc[c] = 0.f;
  for (int k = 0; k < F_H; ++k) {
    float xv = hs[node * 68 + k];
#pragma unroll
    for (int c = 0; c < 10; ++c) acc[c] += xv * w2s[k * NC + cg * 10 + c];
  }
  const int gn = nb + node;
  float ps = 0.f, pd = 0.f;
#pragma unroll
  for (int c = 0; c < 10; ++c) {
    ps += acc[c] * a_src2[cg * 10 + c];
    pd += acc[c] * a_dst2[cg * 10 + c];
  }
  ps += __shfl_xor(ps, 1); ps += __shfl_xor(ps, 2);
  pd += __shfl_xor(pd, 1); pd += __shfl_xor(pd, 2);
  if (gn < N_NODES) {
#pragma unroll
    for (int c = 0; c < 10; ++c) h2b[(size_t)gn * NC + cg * 10 + c] = f2bf(acc[c]);
    if (cg == 0) { als2[gn] = ps; ald2[gn] = pd; }
  }
}

// ---------------------------------------------------------------------------
// Layer-2 aggregation + bias + log_softmax. Wave = 8 nodes x 8 lanes;
// lanes l<5 each carry 8 classes (one dwordx4 bf16 gather). Unroll x4.
// ---------------------------------------------------------------------------
__global__ __launch_bounds__(256) void k_agg2n(
    const int* __restrict__ rowstart, const int* __restrict__ csrc,
    const unsigned short* __restrict__ h2b, const float* __restrict__ als2,
    const float* __restrict__ ald2, const float* __restrict__ b2,
    float* __restrict__ out) {
  const int w = (int)((blockIdx.x * 256 + threadIdx.x) >> 6);
  const int lane = threadIdx.x & 63;
  const int grp = lane >> 3;
  const int l = lane & 7;
  const int n = w * 8 + grp;
  const bool live = (n < N_NODES);
  const int e0 = live ? rowstart[n] : 0;
  const int e1 = live ? rowstart[n + 1] : 0;
  const float aldv = live ? ald2[n] : 0.f;
  const bool act = (l < 5);
  const int fo = act ? l * 8 : 0;

  float den = 0.f;
  float acc[8];
#pragma unroll
  for (int k = 0; k < 8; ++k) acc[k] = 0.f;

  int e = e0;
  for (; e + 4 <= e1; e += 4) {
    int4 sv = *reinterpret_cast<const int4*>(&csrc[e]);
    float a0 = als2[sv.x], a1 = als2[sv.y], a2 = als2[sv.z], a3 = als2[sv.w];
    uint4 u0 = *reinterpret_cast<const uint4*>(&h2b[(size_t)sv.x * NC + fo]);
    uint4 u1 = *reinterpret_cast<const uint4*>(&h2b[(size_t)sv.y * NC + fo]);
    uint4 u2 = *reinterpret_cast<const uint4*>(&h2b[(size_t)sv.z * NC + fo]);
    uint4 u3 = *reinterpret_cast<const uint4*>(&h2b[(size_t)sv.w * NC + fo]);
    float p0 = lrexp(a0 + aldv), p1 = lrexp(a1 + aldv);
    float p2 = lrexp(a2 + aldv), p3 = lrexp(a3 + aldv);
    den += (p0 + p1) + (p2 + p3);
    const unsigned int* q0 = &u0.x;
    const unsigned int* q1 = &u1.x;
    const unsigned int* q2 = &u2.x;
    const unsigned int* q3 = &u3.x;
#pragma unroll
    for (int k = 0; k < 4; ++k) {
      acc[2 * k]     += p0 * bf2f((unsigned short)q0[k]) + p1 * bf2f((unsigned short)q1[k])
                      + p2 * bf2f((unsigned short)q2[k]) + p3 * bf2f((unsigned short)q3[k]);
      acc[2 * k + 1] += p0 * bf2f((unsigned short)(q0[k] >> 16)) + p1 * bf2f((unsigned short)(q1[k] >> 16))
                      + p2 * bf2f((unsigned short)(q2[k] >> 16)) + p3 * bf2f((unsigned short)(q3[k] >> 16));
    }
  }
  for (; e < e1; ++e) {
    int s = csrc[e];
    float a = als2[s];
    uint4 u = *reinterpret_cast<const uint4*>(&h2b[(size_t)s * NC + fo]);
    float p = lrexp(a + aldv);
    den += p;
    const unsigned int* q = &u.x;
#pragma unroll
    for (int k = 0; k < 4; ++k) {
      acc[2 * k]     += p * bf2f((unsigned short)q[k]);
      acc[2 * k + 1] += p * bf2f((unsigned short)(q[k] >> 16));
    }
  }

  float o[8];
  float inv = 1.f / den;
  float mx = -1e30f;
#pragma unroll
  for (int k = 0; k < 8; ++k) {
    o[k] = act ? (acc[k] * inv + b2[fo + k]) : -1e30f;
    mx = fmaxf(mx, o[k]);
  }
  mx = fmaxf(mx, __shfl_xor(mx, 1));
  mx = fmaxf(mx, __shfl_xor(mx, 2));
  mx = fmaxf(mx, __shfl_xor(mx, 4));
  float se = 0.f;
#pragma unroll
  for (int k = 0; k < 8; ++k) se += act ? __expf(o[k] - mx) : 0.f;
  se += __shfl_xor(se, 1);
  se += __shfl_xor(se, 2);
  se += __shfl_xor(se, 4);
  if (live && act) {
    float ls = __logf(se);
    float4 r0, r1;
    r0.x = o[0] - mx - ls; r0.y = o[1] - mx - ls;
    r0.z = o[2] - mx - ls; r0.w = o[3] - mx - ls;
    r1.x = o[4] - mx - ls; r1.y = o[5] - mx - ls;
    r1.z = o[6] - mx - ls; r1.w = o[7] - mx - ls;
    *reinterpret_cast<float4*>(&out[(size_t)n * NC + l * 8]) = r0;
    *reinterpret_cast<float4*>(&out[(size_t)n * NC + l * 8 + 4]) = r1;
  }
}

// ---------------------------------------------------------------------------
extern "C" void kernel_launch(void* const* d_in, const int* in_sizes, int n_in,
                              void* d_out, int out_size, void* d_ws, size_t ws_size,
                              hipStream_t stream) {
  const float* x      = (const float*)d_in[0];
  const int*   ei     = (const int*)d_in[1];
  const float* W1     = (const float*)d_in[2];
  const float* a_src1 = (const float*)d_in[3];
  const float* a_dst1 = (const float*)d_in[4];
  const float* b1     = (const float*)d_in[5];
  const float* W2     = (const float*)d_in[6];
  const float* a_src2 = (const float*)d_in[7];
  const float* a_dst2 = (const float*)d_in[8];
  const float* b2     = (const float*)d_in[9];
  float* out = (float*)d_out;

  char* ws = (char*)d_ws;
  size_t o = 0;
  auto carve = [&](size_t bytes) -> char* {
    char* p = ws + o;
    o = (o + bytes + 255) & ~(size_t)255;
    return p;
  };
  int*   bcnt     = (int*)carve((size_t)NB * 4);
  int*   bstart   = (int*)carve((size_t)(NB + 1) * 4);
  int*   bcur     = (int*)carve((size_t)NB * 4);
  int*   rowstart = (int*)carve((size_t)(N_NODES + 1) * 4);
  unsigned int* inter = (unsigned int*)carve((size_t)E_TOT * 4);
  int*   csrc     = (int*)carve((size_t)(E_TOT + 8) * 4);   // +pad for int4 tail read
  uint4* w1f      = (uint4*)carve((size_t)4096 * 16);
  unsigned short* h1b   = (unsigned short*)carve((size_t)N_NODES * F_H * 2);
  float* als1     = (float*)carve((size_t)N_NODES * HEADS * 4);
  float* ald1     = (float*)carve((size_t)N_NODES * HEADS * 4);
  unsigned short* hactb = (unsigned short*)carve((size_t)N_NODES * F_H * 2);
  unsigned short* h2b   = (unsigned short*)carve((size_t)(N_NODES * NC + 8) * 2);
  float* als2     = (float*)carve((size_t)N_NODES * 4);
  float* ald2     = (float*)carve((size_t)N_NODES * 4);
  (void)ws_size; (void)n_in; (void)in_sizes; (void)out_size;

  hipMemsetAsync(bcnt, 0, (size_t)NB * 4, stream);
  k_hist_pack<<<16 + NBH, 256, 0, stream>>>(ei, W1, w1f, bcnt);
  k_bscan<<<1, 512, 0, stream>>>(bcnt, bstart, bcur, rowstart);
  k_bfill<<<NBF, 256, 0, stream>>>(ei, bcur, inter);
  k_gemm1r<<<GEMM_G, 256, 0, stream>>>(x, w1f, a_src1, a_dst1, h1b, als1, ald1);
  k_cfill<<<NB, 256, 0, stream>>>(inter, bstart, rowstart, csrc);

  const int aggGrid = (N_NODES + 31) / 32;   // 8 nodes/wave, 4 waves/block
  k_agg1n<<<aggGrid, 256, 0, stream>>>(rowstart, csrc, h1b, als1, ald1, b1, hactb);
  k_l2proj<<<(N_NODES + 63) / 64, 256, 0, stream>>>(hactb, W2, a_src2, a_dst2, h2b, als2, ald2);
  k_agg2n<<<aggGrid, 256, 0, stream>>>(rowstart, csrc, h2b, als2, ald2, b2, out);
}

// Round 14
// 251.347 us; speedup vs baseline: 1.4984x; 1.0561x over previous
//
#include <hip/hip_runtime.h>
#include <hip/hip_bf16.h>
#include <cstdint>
#include <cstddef>

#define N_NODES 100000
#define N_EDGES 1600000
#define E_TOT   (N_EDGES + N_NODES)
#define F_IN    512
#define HEADS   8
#define HID     8
#define F_H     64          // HEADS*HID
#define NC      40
#define NEG     0.2f

#define BSH    8            // bucket = dst >> 8 (256 nodes/bucket)
#define NB     391          // ceil(100000/256)
#define CHUNKH 8192         // edges per bhist block
#define NBH    ((E_TOT + CHUNKH - 1) / CHUNKH)   // 208
#define CHUNKF 4096         // edges per bfill block (16KB LDS staging)
#define NBF    ((E_TOT + CHUNKF - 1) / CHUNKF)   // 416
#define CAP    7168         // k_cfill LDS staging entries (avg seg ~4350)
#define GEMM_G ((N_NODES + 63) / 64)             // 1563 gemm blocks
#define FG_T   (GEMM_G + NBF)                    // 1979 blocks in fat kernel
#define FG_R1  (NBF * 4)                         // 1664: interleave region

typedef __attribute__((ext_vector_type(8))) __bf16 bf16x8;
typedef __attribute__((ext_vector_type(4))) float f32x4;
typedef __attribute__((ext_vector_type(8))) unsigned short u16x8;

__device__ __forceinline__ float bf2f(unsigned short u) {
  unsigned int w = ((unsigned int)u) << 16;
  return __builtin_bit_cast(float, w);
}
__device__ __forceinline__ unsigned short f2bf(float f) {
  __hip_bfloat16 b = __float2bfloat16(f);
  return __builtin_bit_cast(unsigned short, b);
}
__device__ __forceinline__ float lrexp(float v) {
  v = (v > 0.f) ? v : NEG * v;
  return __expf(v);
}

// Per-block edge_index dtype probe: int64 layout -> high int32 words of the
// first 64 entries are all 0. One wave-wide ballot, L2-hot after first block.
__device__ __forceinline__ bool detect_i64(const int* __restrict__ ei) {
  int lane = threadIdx.x & 63;
  int v = ei[2 * lane + 1];
  return __ballot(v != 0) == 0ull;
}

__device__ __forceinline__ int load_dst(const int* __restrict__ ei, bool f, int i) {
  if (i < N_EDGES) return f ? ei[2 * (N_EDGES + i)] : ei[N_EDGES + i];
  return i - N_EDGES;
}
__device__ __forceinline__ int load_src(const int* __restrict__ ei, bool f, int i) {
  if (i < N_EDGES) return f ? ei[2 * i] : ei[i];
  return i - N_EDGES;
}

// ---------------------------------------------------------------------------
// Fat kernel A: blocks [0,16) pack W1 -> bf16 B-fragment-major; blocks
// [16,16+NBH) histogram dst buckets (LDS-binned).
// ---------------------------------------------------------------------------
__global__ __launch_bounds__(256) void k_hist_pack(
    const int* __restrict__ ei, const float* __restrict__ W1,
    uint4* __restrict__ w1f, int* __restrict__ bcnt) {
  __shared__ int h[NB];
  const int t = threadIdx.x;
  if (blockIdx.x < 16) {
    int tid = blockIdx.x * 256 + t;   // 0..4095
    int lane = tid & 63;
    int tt = (tid >> 6) & 3;
    int s = tid >> 8;
    int k0 = s * 32 + ((lane >> 4) << 3);
    int col = tt * 16 + (lane & 15);
    u16x8 v;
#pragma unroll
    for (int i = 0; i < 8; ++i) v[i] = f2bf(W1[(size_t)(k0 + i) * F_H + col]);
    w1f[tid] = __builtin_bit_cast(uint4, v);
    return;
  }
  const int blk = blockIdx.x - 16;
  const bool f = detect_i64(ei);
  for (int i = t; i < NB; i += 256) h[i] = 0;
  __syncthreads();
  const int base = blk * CHUNKH;
#pragma unroll
  for (int j = 0; j < CHUNKH / 256; ++j) {
    int i = base + t + j * 256;
    if (i < E_TOT) atomicAdd(&h[load_dst(ei, f, i) >> BSH], 1);
  }
  __syncthreads();
  for (int i = t; i < NB; i += 256)
    if (h[i]) atomicAdd(&bcnt[i], h[i]);
}

// ---------------------------------------------------------------------------
// Fat kernel B: gemm1m blocks interleaved with bfill blocks (every 4th block
// in the first FG_R1 blocks is bfill). bfill computes the bucket prefix scan
// LOCALLY from bcnt (no separate bscan kernel); bcur is zero-seeded, global
// position = bst[i] + atomicAdd(&bcur[i], h[i]).
// ---------------------------------------------------------------------------
__global__ __launch_bounds__(256) void k_fill_gemm(
    const int* __restrict__ ei, const int* __restrict__ bcnt,
    int* __restrict__ bcur, unsigned int* __restrict__ inter,
    const float* __restrict__ x, const uint4* __restrict__ w1f,
    const float* __restrict__ a_src, const float* __restrict__ a_dst,
    unsigned short* __restrict__ h1b, float* __restrict__ als,
    float* __restrict__ ald) {
  __shared__ unsigned int ent[CHUNKF];                       // 16 KB
  __shared__ int h[NB], ofs[NB], cur[NB], gpos[NB], bst[NB]; // ~7.8 KB
  const int b = (int)blockIdx.x;
  const int t = threadIdx.x;
  bool isFill;
  int idx;
  if (b < FG_R1) {
    if ((b & 3) == 3) { isFill = true;  idx = b >> 2; }
    else              { isFill = false; idx = b - (b >> 2); }
  } else {
    isFill = false; idx = b - NBF;
  }

  if (isFill) {
    // ---- bfill(idx) ----
    const bool f = detect_i64(ei);
    const int base = idx * CHUNKF;
    for (int i = t; i < NB; i += 256) h[i] = 0;
    __syncthreads();
#pragma unroll
    for (int j = 0; j < CHUNKF / 256; ++j) {
      int i = base + t + j * 256;
      if (i < E_TOT) atomicAdd(&h[load_dst(ei, f, i) >> BSH], 1);
    }
    __syncthreads();
    if (t < 64) {
      // local scan of per-block histogram h -> ofs
      int loc[7];
      int s = 0;
#pragma unroll
      for (int k = 0; k < 7; ++k) {
        int ix = t * 7 + k;
        int hv = (ix < NB) ? h[ix] : 0;
        loc[k] = s;
        s += hv;
      }
      int incl = s;
      for (int dd = 1; dd < 64; dd <<= 1) {
        int u = __shfl_up(incl, dd);
        if (t >= dd) incl += u;
      }
      int excl = incl - s;
#pragma unroll
      for (int k = 0; k < 7; ++k) {
        int ix = t * 7 + k;
        if (ix < NB) ofs[ix] = excl + loc[k];
      }
    } else if (t < 128) {
      // local scan of GLOBAL bucket counts bcnt -> bst (wave 1)
      int tl = t - 64;
      int loc[7];
      int s = 0;
#pragma unroll
      for (int k = 0; k < 7; ++k) {
        int ix = tl * 7 + k;
        int hv = (ix < NB) ? bcnt[ix] : 0;
        loc[k] = s;
        s += hv;
      }
      int incl = s;
      for (int dd = 1; dd < 64; dd <<= 1) {
        int u = __shfl_up(incl, dd);
        if (tl >= dd) incl += u;
      }
      int excl = incl - s;
#pragma unroll
      for (int k = 0; k < 7; ++k) {
        int ix = tl * 7 + k;
        if (ix < NB) bst[ix] = excl + loc[k];
      }
    }
    __syncthreads();
    for (int i = t; i < NB; i += 256) {
      cur[i] = ofs[i];
      gpos[i] = h[i] ? (bst[i] + atomicAdd(&bcur[i], h[i])) : 0;
    }
    __syncthreads();
#pragma unroll
    for (int j = 0; j < CHUNKF / 256; ++j) {
      int i = base + t + j * 256;
      if (i < E_TOT) {
        int s = load_src(ei, f, i);
        int d = load_dst(ei, f, i);
        int p = atomicAdd(&cur[d >> BSH], 1);
        ent[p] = ((unsigned int)(d & 255) << 24) | (unsigned int)s;
      }
    }
    __syncthreads();
    const int wv = t >> 6, ln = t & 63;
    for (int bb = wv; bb < NB; bb += 4) {
      int c = h[bb];
      if (!c) continue;
      int g = gpos[bb], o = ofs[bb];
      for (int i = ln; i < c; i += 64) inter[g + i] = ent[o + i];
    }
    return;
  }

  // ---- gemm1m(idx): reg-direct MFMA, fused logits ----
  const int lane = t & 63;
  const int wv = t >> 6;
  const int rb = idx * 64 + wv * 16;
  int arow = rb + (lane & 15);
  if (arow >= N_NODES) arow = N_NODES - 1;   // clamp; stores predicated
  const float* aptr = x + (size_t)arow * F_IN + ((lane >> 4) << 3);

  f32x4 acc[4];
#pragma unroll
  for (int i = 0; i < 4; ++i) acc[i] = (f32x4){0.f, 0.f, 0.f, 0.f};

#pragma unroll 4
  for (int s = 0; s < 16; ++s) {
    float4 a0 = *reinterpret_cast<const float4*>(aptr + s * 32);
    float4 a1 = *reinterpret_cast<const float4*>(aptr + s * 32 + 4);
    uint4 b0 = w1f[(s * 4 + 0) * 64 + lane];
    uint4 b1 = w1f[(s * 4 + 1) * 64 + lane];
    uint4 b2 = w1f[(s * 4 + 2) * 64 + lane];
    uint4 b3 = w1f[(s * 4 + 3) * 64 + lane];
    bf16x8 af;
    af[0] = (__bf16)a0.x; af[1] = (__bf16)a0.y;
    af[2] = (__bf16)a0.z; af[3] = (__bf16)a0.w;
    af[4] = (__bf16)a1.x; af[5] = (__bf16)a1.y;
    af[6] = (__bf16)a1.z; af[7] = (__bf16)a1.w;
    acc[0] = __builtin_amdgcn_mfma_f32_16x16x32_bf16(af, __builtin_bit_cast(bf16x8, b0), acc[0], 0, 0, 0);
    acc[1] = __builtin_amdgcn_mfma_f32_16x16x32_bf16(af, __builtin_bit_cast(bf16x8, b1), acc[1], 0, 0, 0);
    acc[2] = __builtin_amdgcn_mfma_f32_16x16x32_bf16(af, __builtin_bit_cast(bf16x8, b2), acc[2], 0, 0, 0);
    acc[3] = __builtin_amdgcn_mfma_f32_16x16x32_bf16(af, __builtin_bit_cast(bf16x8, b3), acc[3], 0, 0, 0);
  }

  const int r0 = rb + ((lane >> 4) << 2);
  const int c = lane & 15;
#pragma unroll
  for (int tt = 0; tt < 4; ++tt) {
#pragma unroll
    for (int i = 0; i < 4; ++i) {
      int r = r0 + i;
      if (r < N_NODES) h1b[(size_t)r * F_H + tt * 16 + c] = f2bf(acc[tt][i]);
    }
  }

  float asw[4], adw[4];
#pragma unroll
  for (int tt = 0; tt < 4; ++tt) {
    asw[tt] = a_src[tt * 16 + c];
    adw[tt] = a_dst[tt * 16 + c];
  }
  float sp[4][4], dp[4][4];
#pragma unroll
  for (int tt = 0; tt < 4; ++tt)
#pragma unroll
    for (int i = 0; i < 4; ++i) {
      sp[tt][i] = acc[tt][i] * asw[tt];
      dp[tt][i] = acc[tt][i] * adw[tt];
    }
#pragma unroll
  for (int dd = 1; dd < 8; dd <<= 1)
#pragma unroll
    for (int tt = 0; tt < 4; ++tt)
#pragma unroll
      for (int i = 0; i < 4; ++i) {
        sp[tt][i] += __shfl_xor(sp[tt][i], dd);
        dp[tt][i] += __shfl_xor(dp[tt][i], dd);
      }
  if ((c & 7) == 0) {
    const int hb = c >> 3;
#pragma unroll
    for (int i = 0; i < 4; ++i) {
      int r = r0 + i;
      if (r < N_NODES) {
#pragma unroll
        for (int tt = 0; tt < 4; ++tt) {
          als[(size_t)r * HEADS + tt * 2 + hb] = sp[tt][i];
          ald[(size_t)r * HEADS + tt * 2 + hb] = dp[tt][i];
        }
      }
    }
  }
}

// ---------------------------------------------------------------------------
// One block per bucket; LDS counting sort -> csrc + rowstart coalesced.
// segStart computed locally: block-reduce prefix of bcnt[0..b); L = bcnt[b].
// ---------------------------------------------------------------------------
__global__ __launch_bounds__(256) void k_cfill(const unsigned int* __restrict__ inter,
                                               const int* __restrict__ bcnt,
                                               int* __restrict__ rowstart,
                                               int* __restrict__ csrc) {
  __shared__ unsigned int out_l[CAP];      // 28 KB
  __shared__ int cnt[256], sc[256], cur2[256], red[256];
  const int t = threadIdx.x;
  const int b = blockIdx.x;

  int partial = 0;
  for (int i = t; i < b; i += 256) partial += bcnt[i];
  red[t] = partial;
  cnt[t] = 0;
  __syncthreads();
  for (int d = 128; d > 0; d >>= 1) {
    if (t < d) red[t] += red[t + d];
    __syncthreads();
  }
  const int segStart = red[0];
  const int L = bcnt[b];
  if (b == 0 && t == 0) rowstart[N_NODES] = E_TOT;

  for (int i = t; i < L; i += 256) atomicAdd(&cnt[inter[segStart + i] >> 24], 1);
  __syncthreads();
  sc[t] = cnt[t];
  __syncthreads();
  for (int d = 1; d < 256; d <<= 1) {
    int v = (t >= d) ? sc[t - d] : 0;
    __syncthreads();
    sc[t] += v;
    __syncthreads();
  }
  const int excl = sc[t] - cnt[t];
  cur2[t] = excl;
  const int node = (b << BSH) + t;
  if (node < N_NODES) rowstart[node] = segStart + excl;
  __syncthreads();
  if (L <= CAP) {
    for (int i = t; i < L; i += 256) {
      unsigned int e = inter[segStart + i];
      int p = atomicAdd(&cur2[e >> 24], 1);
      out_l[p] = e & 0xFFFFFFu;
    }
    __syncthreads();
    for (int i = t; i < L; i += 256) csrc[segStart + i] = (int)out_l[i];
  } else {  // safety fallback (statistically never taken)
    for (int i = t; i < L; i += 256) {
      unsigned int e = inter[segStart + i];
      int p = atomicAdd(&cur2[e >> 24], 1);
      csrc[segStart + p] = (int)(e & 0xFFFFFFu);
    }
  }
}

// ---------------------------------------------------------------------------
// Layer-1 aggregation: wave = 8 nodes x 8 lanes. Lane = head = 8 features
// (one dwordx4 of bf16 per edge). Unroll x4 -> 32 gathers in flight per wave.
// ---------------------------------------------------------------------------
__global__ __launch_bounds__(256) void k_agg1n(
    const int* __restrict__ rowstart, const int* __restrict__ csrc,
    const unsigned short* __restrict__ h1b, const float* __restrict__ als,
    const float* __restrict__ ald, const float* __restrict__ b1,
    unsigned short* __restrict__ hactb) {
  const int w = (int)((blockIdx.x * 256 + threadIdx.x) >> 6);
  const int lane = threadIdx.x & 63;
  const int grp = lane >> 3;        // node slot 0..7
  const int l = lane & 7;           // head / feature octet
  const int n = w * 8 + grp;
  const bool live = (n < N_NODES);
  const int e0 = live ? rowstart[n] : 0;
  const int e1 = live ? rowstart[n + 1] : 0;
  const float aldv = live ? ald[(size_t)n * HEADS + l] : 0.f;

  float den = 0.f;
  float acc[8];
#pragma unroll
  for (int k = 0; k < 8; ++k) acc[k] = 0.f;

  int e = e0;
  for (; e + 4 <= e1; e += 4) {
    int4 sv = *reinterpret_cast<const int4*>(&csrc[e]);
    float a0 = als[(size_t)sv.x * HEADS + l];
    float a1 = als[(size_t)sv.y * HEADS + l];
    float a2 = als[(size_t)sv.z * HEADS + l];
    float a3 = als[(size_t)sv.w * HEADS + l];
    uint4 u0 = *reinterpret_cast<const uint4*>(&h1b[(size_t)sv.x * F_H + l * 8]);
    uint4 u1 = *reinterpret_cast<const uint4*>(&h1b[(size_t)sv.y * F_H + l * 8]);
    uint4 u2 = *reinterpret_cast<const uint4*>(&h1b[(size_t)sv.z * F_H + l * 8]);
    uint4 u3 = *reinterpret_cast<const uint4*>(&h1b[(size_t)sv.w * F_H + l * 8]);
    float p0 = lrexp(a0 + aldv), p1 = lrexp(a1 + aldv);
    float p2 = lrexp(a2 + aldv), p3 = lrexp(a3 + aldv);
    den += (p0 + p1) + (p2 + p3);
    const unsigned int* q0 = &u0.x;
    const unsigned int* q1 = &u1.x;
    const unsigned int* q2 = &u2.x;
    const unsigned int* q3 = &u3.x;
#pragma unroll
    for (int k = 0; k < 4; ++k) {
      acc[2 * k]     += p0 * bf2f((unsigned short)q0[k]) + p1 * bf2f((unsigned short)q1[k])
                      + p2 * bf2f((unsigned short)q2[k]) + p3 * bf2f((unsigned short)q3[k]);
      acc[2 * k + 1] += p0 * bf2f((unsigned short)(q0[k] >> 16)) + p1 * bf2f((unsigned short)(q1[k] >> 16))
                      + p2 * bf2f((unsigned short)(q2[k] >> 16)) + p3 * bf2f((unsigned short)(q3[k] >> 16));
    }
  }
  for (; e < e1; ++e) {
    int s = csrc[e];
    float a = als[(size_t)s * HEADS + l];
    uint4 u = *reinterpret_cast<const uint4*>(&h1b[(size_t)s * F_H + l * 8]);
    float p = lrexp(a + aldv);
    den += p;
    const unsigned int* q = &u.x;
#pragma unroll
    for (int k = 0; k < 4; ++k) {
      acc[2 * k]     += p * bf2f((unsigned short)q[k]);
      acc[2 * k + 1] += p * bf2f((unsigned short)(q[k] >> 16));
    }
  }

  if (live) {
    float inv = 1.f / den;
    uint4 outw;
    unsigned int* ow = &outw.x;
#pragma unroll
    for (int k = 0; k < 4; ++k) {
      float ox = acc[2 * k] * inv + b1[l * 8 + 2 * k];
      float oy = acc[2 * k + 1] * inv + b1[l * 8 + 2 * k + 1];
      ox = (ox > 0.f) ? ox : expm1f(ox);
      oy = (oy > 0.f) ? oy : expm1f(oy);
      ow[k] = ((unsigned int)f2bf(oy) << 16) | (unsigned int)f2bf(ox);
    }
    *reinterpret_cast<uint4*>(&hactb[(size_t)n * F_H + l * 8]) = outw;
  }
}

// ---------------------------------------------------------------------------
// Layer-2 projection: h2 = hact @ W2 (64x40) + attention logits (1 head).
// ---------------------------------------------------------------------------
__global__ __launch_bounds__(256) void k_l2proj(
    const unsigned short* __restrict__ hactb, const float* __restrict__ W2,
    const float* __restrict__ a_src2, const float* __restrict__ a_dst2,
    unsigned short* __restrict__ h2b, float* __restrict__ als2,
    float* __restrict__ ald2) {
  __shared__ float hs[64 * 68];
  __shared__ float w2s[F_H * NC];
  const int t = threadIdx.x;
  const int nb = blockIdx.x * 64;
  {
    int r0 = t >> 3, c8 = t & 7;
#pragma unroll
    for (int i = 0; i < 2; ++i) {
      int r = r0 + i * 32;
      int gr = nb + r;
      u16x8 v = (u16x8)(0);
      if (gr < N_NODES)
        v = *reinterpret_cast<const u16x8*>(&hactb[(size_t)gr * F_H + c8 * 8]);
#pragma unroll
      for (int k = 0; k < 8; ++k) hs[r * 68 + c8 * 8 + k] = bf2f(v[k]);
    }
  }
  for (int i = t; i < F_H * NC; i += 256) w2s[i] = W2[i];
  __syncthreads();

  const int node = t >> 2, cg = t & 3;
  float acc[10];
#pragma unroll
  for (int c = 0; c < 10; ++c) acc[c] = 0.f;
  for (int k = 0; k < F_H; ++k) {
    float xv = hs[node * 68 + k];
#pragma unroll
    for (int c = 0; c < 10; ++c) acc[c] += xv * w2s[k * NC + cg * 10 + c];
  }
  const int gn = nb + node;
  float ps = 0.f, pd = 0.f;
#pragma unroll
  for (int c = 0; c < 10; ++c) {
    ps += acc[c] * a_src2[cg * 10 + c];
    pd += acc[c] * a_dst2[cg * 10 + c];
  }
  ps += __shfl_xor(ps, 1); ps += __shfl_xor(ps, 2);
  pd += __shfl_xor(pd, 1); pd += __shfl_xor(pd, 2);
  if (gn < N_NODES) {
#pragma unroll
    for (int c = 0; c < 10; ++c) h2b[(size_t)gn * NC + cg * 10 + c] = f2bf(acc[c]);
    if (cg == 0) { als2[gn] = ps; ald2[gn] = pd; }
  }
}

// ---------------------------------------------------------------------------
// Layer-2 aggregation + bias + log_softmax. Wave = 8 nodes x 8 lanes;
// lanes l<5 each carry 8 classes (one dwordx4 bf16 gather). Unroll x4.
// ---------------------------------------------------------------------------
__global__ __launch_bounds__(256) void k_agg2n(
    const int* __restrict__ rowstart, const int* __restrict__ csrc,
    const unsigned short* __restrict__ h2b, const float* __restrict__ als2,
    const float* __restrict__ ald2, const float* __restrict__ b2,
    float* __restrict__ out) {
  const int w = (int)((blockIdx.x * 256 + threadIdx.x) >> 6);
  const int lane = threadIdx.x & 63;
  const int grp = lane >> 3;
  const int l = lane & 7;
  const int n = w * 8 + grp;
  const bool live = (n < N_NODES);
  const int e0 = live ? rowstart[n] : 0;
  const int e1 = live ? rowstart[n + 1] : 0;
  const float aldv = live ? ald2[n] : 0.f;
  const bool act = (l < 5);
  const int fo = act ? l * 8 : 0;

  float den = 0.f;
  float acc[8];
#pragma unroll
  for (int k = 0; k < 8; ++k) acc[k] = 0.f;

  int e = e0;
  for (; e + 4 <= e1; e += 4) {
    int4 sv = *reinterpret_cast<const int4*>(&csrc[e]);
    float a0 = als2[sv.x], a1 = als2[sv.y], a2 = als2[sv.z], a3 = als2[sv.w];
    uint4 u0 = *reinterpret_cast<const uint4*>(&h2b[(size_t)sv.x * NC + fo]);
    uint4 u1 = *reinterpret_cast<const uint4*>(&h2b[(size_t)sv.y * NC + fo]);
    uint4 u2 = *reinterpret_cast<const uint4*>(&h2b[(size_t)sv.z * NC + fo]);
    uint4 u3 = *reinterpret_cast<const uint4*>(&h2b[(size_t)sv.w * NC + fo]);
    float p0 = lrexp(a0 + aldv), p1 = lrexp(a1 + aldv);
    float p2 = lrexp(a2 + aldv), p3 = lrexp(a3 + aldv);
    den += (p0 + p1) + (p2 + p3);
    const unsigned int* q0 = &u0.x;
    const unsigned int* q1 = &u1.x;
    const unsigned int* q2 = &u2.x;
    const unsigned int* q3 = &u3.x;
#pragma unroll
    for (int k = 0; k < 4; ++k) {
      acc[2 * k]     += p0 * bf2f((unsigned short)q0[k]) + p1 * bf2f((unsigned short)q1[k])
                      + p2 * bf2f((unsigned short)q2[k]) + p3 * bf2f((unsigned short)q3[k]);
      acc[2 * k + 1] += p0 * bf2f((unsigned short)(q0[k] >> 16)) + p1 * bf2f((unsigned short)(q1[k] >> 16))
                      + p2 * bf2f((unsigned short)(q2[k] >> 16)) + p3 * bf2f((unsigned short)(q3[k] >> 16));
    }
  }
  for (; e < e1; ++e) {
    int s = csrc[e];
    float a = als2[s];
    uint4 u = *reinterpret_cast<const uint4*>(&h2b[(size_t)s * NC + fo]);
    float p = lrexp(a + aldv);
    den += p;
    const unsigned int* q = &u.x;
#pragma unroll
    for (int k = 0; k < 4; ++k) {
      acc[2 * k]     += p * bf2f((unsigned short)q[k]);
      acc[2 * k + 1] += p * bf2f((unsigned short)(q[k] >> 16));
    }
  }

  float o[8];
  float inv = 1.f / den;
  float mx = -1e30f;
#pragma unroll
  for (int k = 0; k < 8; ++k) {
    o[k] = act ? (acc[k] * inv + b2[fo + k]) : -1e30f;
    mx = fmaxf(mx, o[k]);
  }
  mx = fmaxf(mx, __shfl_xor(mx, 1));
  mx = fmaxf(mx, __shfl_xor(mx, 2));
  mx = fmaxf(mx, __shfl_xor(mx, 4));
  float se = 0.f;
#pragma unroll
  for (int k = 0; k < 8; ++k) se += act ? __expf(o[k] - mx) : 0.f;
  se += __shfl_xor(se, 1);
  se += __shfl_xor(se, 2);
  se += __shfl_xor(se, 4);
  if (live && act) {
    float ls = __logf(se);
    float4 r0, r1;
    r0.x = o[0] - mx - ls; r0.y = o[1] - mx - ls;
    r0.z = o[2] - mx - ls; r0.w = o[3] - mx - ls;
    r1.x = o[4] - mx - ls; r1.y = o[5] - mx - ls;
    r1.z = o[6] - mx - ls; r1.w = o[7] - mx - ls;
    *reinterpret_cast<float4*>(&out[(size_t)n * NC + l * 8]) = r0;
    *reinterpret_cast<float4*>(&out[(size_t)n * NC + l * 8 + 4]) = r1;
  }
}

// ---------------------------------------------------------------------------
extern "C" void kernel_launch(void* const* d_in, const int* in_sizes, int n_in,
                              void* d_out, int out_size, void* d_ws, size_t ws_size,
                              hipStream_t stream) {
  const float* x      = (const float*)d_in[0];
  const int*   ei     = (const int*)d_in[1];
  const float* W1     = (const float*)d_in[2];
  const float* a_src1 = (const float*)d_in[3];
  const float* a_dst1 = (const float*)d_in[4];
  const float* b1     = (const float*)d_in[5];
  const float* W2     = (const float*)d_in[6];
  const float* a_src2 = (const float*)d_in[7];
  const float* a_dst2 = (const float*)d_in[8];
  const float* b2     = (const float*)d_in[9];
  float* out = (float*)d_out;

  char* ws = (char*)d_ws;
  size_t o = 0;
  auto carve = [&](size_t bytes) -> char* {
    char* p = ws + o;
    o = (o + bytes + 255) & ~(size_t)255;
    return p;
  };
  int*   bcnt     = (int*)carve((size_t)NB * 8);   // bcnt + bcur contiguous
  int*   bcur     = bcnt + NB;
  int*   rowstart = (int*)carve((size_t)(N_NODES + 1) * 4);
  unsigned int* inter = (unsigned int*)carve((size_t)E_TOT * 4);
  int*   csrc     = (int*)carve((size_t)(E_TOT + 8) * 4);   // +pad for int4 tail read
  uint4* w1f      = (uint4*)carve((size_t)4096 * 16);
  unsigned short* h1b   = (unsigned short*)carve((size_t)N_NODES * F_H * 2);
  float* als1     = (float*)carve((size_t)N_NODES * HEADS * 4);
  float* ald1     = (float*)carve((size_t)N_NODES * HEADS * 4);
  unsigned short* hactb = (unsigned short*)carve((size_t)N_NODES * F_H * 2);
  unsigned short* h2b   = (unsigned short*)carve((size_t)(N_NODES * NC + 8) * 2);
  float* als2     = (float*)carve((size_t)N_NODES * 4);
  float* ald2     = (float*)carve((size_t)N_NODES * 4);
  (void)ws_size; (void)n_in; (void)in_sizes; (void)out_size;

  hipMemsetAsync(bcnt, 0, (size_t)NB * 8, stream);
  k_hist_pack<<<16 + NBH, 256, 0, stream>>>(ei, W1, w1f, bcnt);
  k_fill_gemm<<<FG_T, 256, 0, stream>>>(ei, bcnt, bcur, inter, x, w1f,
                                        a_src1, a_dst1, h1b, als1, ald1);
  k_cfill<<<NB, 256, 0, stream>>>(inter, bcnt, rowstart, csrc);

  const int aggGrid = (N_NODES + 31) / 32;   // 8 nodes/wave, 4 waves/block
  k_agg1n<<<aggGrid, 256, 0, stream>>>(rowstart, csrc, h1b, als1, ald1, b1, hactb);
  k_l2proj<<<(N_NODES + 63) / 64, 256, 0, stream>>>(hactb, W2, a_src2, a_dst2, h2b, als2, ald2);
  k_agg2n<<<aggGrid, 256, 0, stream>>>(rowstart, csrc, h2b, als2, ald2, b2, out);
}

// Round 16
// 246.444 us; speedup vs baseline: 1.5282x; 1.0199x over previous
//
#include <hip/hip_runtime.h>
#include <hip/hip_bf16.h>
#include <cstdint>
#include <cstddef>

#define N_NODES 100000
#define N_EDGES 1600000
#define E_TOT   (N_EDGES + N_NODES)
#define F_IN    512
#define HEADS   8
#define HID     8
#define F_H     64          // HEADS*HID
#define NC      40
#define NEG     0.2f

#define BSH    8            // bucket = dst >> 8 (256 nodes/bucket)
#define NB     391          // ceil(100000/256)
#define CHUNKH 8192         // edges per bhist block
#define NBH    ((E_TOT + CHUNKH - 1) / CHUNKH)   // 208
#define CHUNKF 4096         // edges per bfill block (16KB LDS staging)
#define NBF    ((E_TOT + CHUNKF - 1) / CHUNKF)   // 416
#define CAP    7168         // k_cfill LDS staging entries (avg seg ~4350)
#define GEMM_G ((N_NODES + 63) / 64)             // 1563 gemm blocks
#define FG_T   (GEMM_G + NBF)                    // 1979 blocks in fat kernel
#define FG_R1  (NBF * 4)                         // 1664: interleave region

typedef __attribute__((ext_vector_type(8))) __bf16 bf16x8;
typedef __attribute__((ext_vector_type(4))) float f32x4;
typedef __attribute__((ext_vector_type(8))) unsigned short u16x8;

__device__ __forceinline__ float bf2f(unsigned short u) {
  unsigned int w = ((unsigned int)u) << 16;
  return __builtin_bit_cast(float, w);
}
__device__ __forceinline__ unsigned short f2bf(float f) {
  __hip_bfloat16 b = __float2bfloat16(f);
  return __builtin_bit_cast(unsigned short, b);
}
__device__ __forceinline__ float lrexp(float v) {
  v = (v > 0.f) ? v : NEG * v;
  return __expf(v);
}

// Per-block edge_index dtype probe: int64 layout -> high int32 words of the
// first 64 entries are all 0. One wave-wide ballot, L2-hot after first block.
__device__ __forceinline__ bool detect_i64(const int* __restrict__ ei) {
  int lane = threadIdx.x & 63;
  int v = ei[2 * lane + 1];
  return __ballot(v != 0) == 0ull;
}

__device__ __forceinline__ int load_dst(const int* __restrict__ ei, bool f, int i) {
  if (i < N_EDGES) return f ? ei[2 * (N_EDGES + i)] : ei[N_EDGES + i];
  return i - N_EDGES;
}
__device__ __forceinline__ int load_src(const int* __restrict__ ei, bool f, int i) {
  if (i < N_EDGES) return f ? ei[2 * i] : ei[i];
  return i - N_EDGES;
}

// ---------------------------------------------------------------------------
// Fat kernel A: blocks [0,16) pack W1 -> bf16 B-fragment-major; blocks
// [16,16+NBH) histogram dst buckets (LDS-binned).
// ---------------------------------------------------------------------------
__global__ __launch_bounds__(256) void k_hist_pack(
    const int* __restrict__ ei, const float* __restrict__ W1,
    uint4* __restrict__ w1f, int* __restrict__ bcnt) {
  __shared__ int h[NB];
  const int t = threadIdx.x;
  if (blockIdx.x < 16) {
    int tid = blockIdx.x * 256 + t;   // 0..4095
    int lane = tid & 63;
    int tt = (tid >> 6) & 3;
    int s = tid >> 8;
    int k0 = s * 32 + ((lane >> 4) << 3);
    int col = tt * 16 + (lane & 15);
    u16x8 v;
#pragma unroll
    for (int i = 0; i < 8; ++i) v[i] = f2bf(W1[(size_t)(k0 + i) * F_H + col]);
    w1f[tid] = __builtin_bit_cast(uint4, v);
    return;
  }
  const int blk = blockIdx.x - 16;
  const bool f = detect_i64(ei);
  for (int i = t; i < NB; i += 256) h[i] = 0;
  __syncthreads();
  const int base = blk * CHUNKH;
#pragma unroll
  for (int j = 0; j < CHUNKH / 256; ++j) {
    int i = base + t + j * 256;
    if (i < E_TOT) atomicAdd(&h[load_dst(ei, f, i) >> BSH], 1);
  }
  __syncthreads();
  for (int i = t; i < NB; i += 256)
    if (h[i]) atomicAdd(&bcnt[i], h[i]);
}

// ---------------------------------------------------------------------------
// Fat kernel B: gemm1m blocks interleaved with bfill blocks (every 4th block
// in the first FG_R1 blocks is bfill). bfill computes the bucket prefix scan
// LOCALLY from bcnt; bcur is zero-seeded, global position = bst + atomicAdd.
// GEMM branch x loads are NON-TEMPORAL (nt): x is read exactly once, and the
// L3-hit service path measured ~2TB/s across 5 GEMM variants; nt streams x
// from HBM instead (evict-first, no IC allocation).
// ---------------------------------------------------------------------------
__global__ __launch_bounds__(256) void k_fill_gemm(
    const int* __restrict__ ei, const int* __restrict__ bcnt,
    int* __restrict__ bcur, unsigned int* __restrict__ inter,
    const float* __restrict__ x, const uint4* __restrict__ w1f,
    const float* __restrict__ a_src, const float* __restrict__ a_dst,
    unsigned short* __restrict__ h1b, float* __restrict__ als,
    float* __restrict__ ald) {
  __shared__ unsigned int ent[CHUNKF];                       // 16 KB
  __shared__ int h[NB], ofs[NB], cur[NB], gpos[NB], bst[NB]; // ~7.8 KB
  const int b = (int)blockIdx.x;
  const int t = threadIdx.x;
  bool isFill;
  int idx;
  if (b < FG_R1) {
    if ((b & 3) == 3) { isFill = true;  idx = b >> 2; }
    else              { isFill = false; idx = b - (b >> 2); }
  } else {
    isFill = false; idx = b - NBF;
  }

  if (isFill) {
    // ---- bfill(idx) ----
    const bool f = detect_i64(ei);
    const int base = idx * CHUNKF;
    for (int i = t; i < NB; i += 256) h[i] = 0;
    __syncthreads();
#pragma unroll
    for (int j = 0; j < CHUNKF / 256; ++j) {
      int i = base + t + j * 256;
      if (i < E_TOT) atomicAdd(&h[load_dst(ei, f, i) >> BSH], 1);
    }
    __syncthreads();
    if (t < 64) {
      // local scan of per-block histogram h -> ofs
      int loc[7];
      int s = 0;
#pragma unroll
      for (int k = 0; k < 7; ++k) {
        int ix = t * 7 + k;
        int hv = (ix < NB) ? h[ix] : 0;
        loc[k] = s;
        s += hv;
      }
      int incl = s;
      for (int dd = 1; dd < 64; dd <<= 1) {
        int u = __shfl_up(incl, dd);
        if (t >= dd) incl += u;
      }
      int excl = incl - s;
#pragma unroll
      for (int k = 0; k < 7; ++k) {
        int ix = t * 7 + k;
        if (ix < NB) ofs[ix] = excl + loc[k];
      }
    } else if (t < 128) {
      // local scan of GLOBAL bucket counts bcnt -> bst (wave 1)
      int tl = t - 64;
      int loc[7];
      int s = 0;
#pragma unroll
      for (int k = 0; k < 7; ++k) {
        int ix = tl * 7 + k;
        int hv = (ix < NB) ? bcnt[ix] : 0;
        loc[k] = s;
        s += hv;
      }
      int incl = s;
      for (int dd = 1; dd < 64; dd <<= 1) {
        int u = __shfl_up(incl, dd);
        if (tl >= dd) incl += u;
      }
      int excl = incl - s;
#pragma unroll
      for (int k = 0; k < 7; ++k) {
        int ix = tl * 7 + k;
        if (ix < NB) bst[ix] = excl + loc[k];
      }
    }
    __syncthreads();
    for (int i = t; i < NB; i += 256) {
      cur[i] = ofs[i];
      gpos[i] = h[i] ? (bst[i] + atomicAdd(&bcur[i], h[i])) : 0;
    }
    __syncthreads();
#pragma unroll
    for (int j = 0; j < CHUNKF / 256; ++j) {
      int i = base + t + j * 256;
      if (i < E_TOT) {
        int s = load_src(ei, f, i);
        int d = load_dst(ei, f, i);
        int p = atomicAdd(&cur[d >> BSH], 1);
        ent[p] = ((unsigned int)(d & 255) << 24) | (unsigned int)s;
      }
    }
    __syncthreads();
    const int wv = t >> 6, ln = t & 63;
    for (int bb = wv; bb < NB; bb += 4) {
      int c = h[bb];
      if (!c) continue;
      int g = gpos[bb], o = ofs[bb];
      for (int i = ln; i < c; i += 64) inter[g + i] = ent[o + i];
    }
    return;
  }

  // ---- gemm1m(idx): reg-direct MFMA, fused logits, nt x loads ----
  const int lane = t & 63;
  const int wv = t >> 6;
  const int rb = idx * 64 + wv * 16;
  int arow = rb + (lane & 15);
  if (arow >= N_NODES) arow = N_NODES - 1;   // clamp; stores predicated
  const float* aptr = x + (size_t)arow * F_IN + ((lane >> 4) << 3);

  f32x4 acc[4];
#pragma unroll
  for (int i = 0; i < 4; ++i) acc[i] = (f32x4){0.f, 0.f, 0.f, 0.f};

#pragma unroll 4
  for (int s = 0; s < 16; ++s) {
    f32x4 a0 = __builtin_nontemporal_load(
        reinterpret_cast<const f32x4*>(aptr + s * 32));
    f32x4 a1 = __builtin_nontemporal_load(
        reinterpret_cast<const f32x4*>(aptr + s * 32 + 4));
    uint4 b0 = w1f[(s * 4 + 0) * 64 + lane];
    uint4 b1 = w1f[(s * 4 + 1) * 64 + lane];
    uint4 b2 = w1f[(s * 4 + 2) * 64 + lane];
    uint4 b3 = w1f[(s * 4 + 3) * 64 + lane];
    bf16x8 af;
    af[0] = (__bf16)a0[0]; af[1] = (__bf16)a0[1];
    af[2] = (__bf16)a0[2]; af[3] = (__bf16)a0[3];
    af[4] = (__bf16)a1[0]; af[5] = (__bf16)a1[1];
    af[6] = (__bf16)a1[2]; af[7] = (__bf16)a1[3];
    acc[0] = __builtin_amdgcn_mfma_f32_16x16x32_bf16(af, __builtin_bit_cast(bf16x8, b0), acc[0], 0, 0, 0);
    acc[1] = __builtin_amdgcn_mfma_f32_16x16x32_bf16(af, __builtin_bit_cast(bf16x8, b1), acc[1], 0, 0, 0);
    acc[2] = __builtin_amdgcn_mfma_f32_16x16x32_bf16(af, __builtin_bit_cast(bf16x8, b2), acc[2], 0, 0, 0);
    acc[3] = __builtin_amdgcn_mfma_f32_16x16x32_bf16(af, __builtin_bit_cast(bf16x8, b3), acc[3], 0, 0, 0);
  }

  const int r0 = rb + ((lane >> 4) << 2);
  const int c = lane & 15;
#pragma unroll
  for (int tt = 0; tt < 4; ++tt) {
#pragma unroll
    for (int i = 0; i < 4; ++i) {
      int r = r0 + i;
      if (r < N_NODES) h1b[(size_t)r * F_H + tt * 16 + c] = f2bf(acc[tt][i]);
    }
  }

  float asw[4], adw[4];
#pragma unroll
  for (int tt = 0; tt < 4; ++tt) {
    asw[tt] = a_src[tt * 16 + c];
    adw[tt] = a_dst[tt * 16 + c];
  }
  float sp[4][4], dp[4][4];
#pragma unroll
  for (int tt = 0; tt < 4; ++tt)
#pragma unroll
    for (int i = 0; i < 4; ++i) {
      sp[tt][i] = acc[tt][i] * asw[tt];
      dp[tt][i] = acc[tt][i] * adw[tt];
    }
#pragma unroll
  for (int dd = 1; dd < 8; dd <<= 1)
#pragma unroll
    for (int tt = 0; tt < 4; ++tt)
#pragma unroll
      for (int i = 0; i < 4; ++i) {
        sp[tt][i] += __shfl_xor(sp[tt][i], dd);
        dp[tt][i] += __shfl_xor(dp[tt][i], dd);
      }
  if ((c & 7) == 0) {
    const int hb = c >> 3;
#pragma unroll
    for (int i = 0; i < 4; ++i) {
      int r = r0 + i;
      if (r < N_NODES) {
#pragma unroll
        for (int tt = 0; tt < 4; ++tt) {
          als[(size_t)r * HEADS + tt * 2 + hb] = sp[tt][i];
          ald[(size_t)r * HEADS + tt * 2 + hb] = dp[tt][i];
        }
      }
    }
  }
}

// ---------------------------------------------------------------------------
// One block per bucket; LDS counting sort -> csrc + rowstart coalesced.
// segStart computed locally: block-reduce prefix of bcnt[0..b); L = bcnt[b].
// ---------------------------------------------------------------------------
__global__ __launch_bounds__(256) void k_cfill(const unsigned int* __restrict__ inter,
                                               const int* __restrict__ bcnt,
                                               int* __restrict__ rowstart,
                                               int* __restrict__ csrc) {
  __shared__ unsigned int out_l[CAP];      // 28 KB
  __shared__ int cnt[256], sc[256], cur2[256], red[256];
  const int t = threadIdx.x;
  const int b = blockIdx.x;

  int partial = 0;
  for (int i = t; i < b; i += 256) partial += bcnt[i];
  red[t] = partial;
  cnt[t] = 0;
  __syncthreads();
  for (int d = 128; d > 0; d >>= 1) {
    if (t < d) red[t] += red[t + d];
    __syncthreads();
  }
  const int segStart = red[0];
  const int L = bcnt[b];
  if (b == 0 && t == 0) rowstart[N_NODES] = E_TOT;

  for (int i = t; i < L; i += 256) atomicAdd(&cnt[inter[segStart + i] >> 24], 1);
  __syncthreads();
  sc[t] = cnt[t];
  __syncthreads();
  for (int d = 1; d < 256; d <<= 1) {
    int v = (t >= d) ? sc[t - d] : 0;
    __syncthreads();
    sc[t] += v;
    __syncthreads();
  }
  const int excl = sc[t] - cnt[t];
  cur2[t] = excl;
  const int node = (b << BSH) + t;
  if (node < N_NODES) rowstart[node] = segStart + excl;
  __syncthreads();
  if (L <= CAP) {
    for (int i = t; i < L; i += 256) {
      unsigned int e = inter[segStart + i];
      int p = atomicAdd(&cur2[e >> 24], 1);
      out_l[p] = e & 0xFFFFFFu;
    }
    __syncthreads();
    for (int i = t; i < L; i += 256) csrc[segStart + i] = (int)out_l[i];
  } else {  // safety fallback (statistically never taken)
    for (int i = t; i < L; i += 256) {
      unsigned int e = inter[segStart + i];
      int p = atomicAdd(&cur2[e >> 24], 1);
      csrc[segStart + p] = (int)(e & 0xFFFFFFu);
    }
  }
}

// ---------------------------------------------------------------------------
// Layer-1 aggregation: wave = 8 nodes x 8 lanes. Lane = head = 8 features
// (one dwordx4 of bf16 per edge). Unroll x4 -> 32 gathers in flight per wave.
// ---------------------------------------------------------------------------
__global__ __launch_bounds__(256) void k_agg1n(
    const int* __restrict__ rowstart, const int* __restrict__ csrc,
    const unsigned short* __restrict__ h1b, const float* __restrict__ als,
    const float* __restrict__ ald, const float* __restrict__ b1,
    unsigned short* __restrict__ hactb) {
  const int w = (int)((blockIdx.x * 256 + threadIdx.x) >> 6);
  const int lane = threadIdx.x & 63;
  const int grp = lane >> 3;        // node slot 0..7
  const int l = lane & 7;           // head / feature octet
  const int n = w * 8 + grp;
  const bool live = (n < N_NODES);
  const int e0 = live ? rowstart[n] : 0;
  const int e1 = live ? rowstart[n + 1] : 0;
  const float aldv = live ? ald[(size_t)n * HEADS + l] : 0.f;

  float den = 0.f;
  float acc[8];
#pragma unroll
  for (int k = 0; k < 8; ++k) acc[k] = 0.f;

  int e = e0;
  for (; e + 4 <= e1; e += 4) {
    int4 sv = *reinterpret_cast<const int4*>(&csrc[e]);
    float a0 = als[(size_t)sv.x * HEADS + l];
    float a1 = als[(size_t)sv.y * HEADS + l];
    float a2 = als[(size_t)sv.z * HEADS + l];
    float a3 = als[(size_t)sv.w * HEADS + l];
    uint4 u0 = *reinterpret_cast<const uint4*>(&h1b[(size_t)sv.x * F_H + l * 8]);
    uint4 u1 = *reinterpret_cast<const uint4*>(&h1b[(size_t)sv.y * F_H + l * 8]);
    uint4 u2 = *reinterpret_cast<const uint4*>(&h1b[(size_t)sv.z * F_H + l * 8]);
    uint4 u3 = *reinterpret_cast<const uint4*>(&h1b[(size_t)sv.w * F_H + l * 8]);
    float p0 = lrexp(a0 + aldv), p1 = lrexp(a1 + aldv);
    float p2 = lrexp(a2 + aldv), p3 = lrexp(a3 + aldv);
    den += (p0 + p1) + (p2 + p3);
    const unsigned int* q0 = &u0.x;
    const unsigned int* q1 = &u1.x;
    const unsigned int* q2 = &u2.x;
    const unsigned int* q3 = &u3.x;
#pragma unroll
    for (int k = 0; k < 4; ++k) {
      acc[2 * k]     += p0 * bf2f((unsigned short)q0[k]) + p1 * bf2f((unsigned short)q1[k])
                      + p2 * bf2f((unsigned short)q2[k]) + p3 * bf2f((unsigned short)q3[k]);
      acc[2 * k + 1] += p0 * bf2f((unsigned short)(q0[k] >> 16)) + p1 * bf2f((unsigned short)(q1[k] >> 16))
                      + p2 * bf2f((unsigned short)(q2[k] >> 16)) + p3 * bf2f((unsigned short)(q3[k] >> 16));
    }
  }
  for (; e < e1; ++e) {
    int s = csrc[e];
    float a = als[(size_t)s * HEADS + l];
    uint4 u = *reinterpret_cast<const uint4*>(&h1b[(size_t)s * F_H + l * 8]);
    float p = lrexp(a + aldv);
    den += p;
    const unsigned int* q = &u.x;
#pragma unroll
    for (int k = 0; k < 4; ++k) {
      acc[2 * k]     += p * bf2f((unsigned short)q[k]);
      acc[2 * k + 1] += p * bf2f((unsigned short)(q[k] >> 16));
    }
  }

  if (live) {
    float inv = 1.f / den;
    uint4 outw;
    unsigned int* ow = &outw.x;
#pragma unroll
    for (int k = 0; k < 4; ++k) {
      float ox = acc[2 * k] * inv + b1[l * 8 + 2 * k];
      float oy = acc[2 * k + 1] * inv + b1[l * 8 + 2 * k + 1];
      ox = (ox > 0.f) ? ox : expm1f(ox);
      oy = (oy > 0.f) ? oy : expm1f(oy);
      ow[k] = ((unsigned int)f2bf(oy) << 16) | (unsigned int)f2bf(ox);
    }
    *reinterpret_cast<uint4*>(&hactb[(size_t)n * F_H + l * 8]) = outw;
  }
}

// ---------------------------------------------------------------------------
// Layer-2 projection: h2 = hact @ W2 (64x40) + attention logits (1 head).
// ---------------------------------------------------------------------------
__global__ __launch_bounds__(256) void k_l2proj(
    const unsigned short* __restrict__ hactb, const float* __restrict__ W2,
    const float* __restrict__ a_src2, const float* __restrict__ a_dst2,
    unsigned short* __restrict__ h2b, float* __restrict__ als2,
    float* __restrict__ ald2) {
  __shared__ float hs[64 * 68];
  __shared__ float w2s[F_H * NC];
  const int t = threadIdx.x;
  const int nb = blockIdx.x * 64;
  {
    int r0 = t >> 3, c8 = t & 7;
#pragma unroll
    for (int i = 0; i < 2; ++i) {
      int r = r0 + i * 32;
      int gr = nb + r;
      u16x8 v = (u16x8)(0);
      if (gr < N_NODES)
        v = *reinterpret_cast<const u16x8*>(&hactb[(size_t)gr * F_H + c8 * 8]);
#pragma unroll
      for (int k = 0; k < 8; ++k) hs[r * 68 + c8 * 8 + k] = bf2f(v[k]);
    }
  }
  for (int i = t; i < F_H * NC; i += 256) w2s[i] = W2[i];
  __syncthreads();

  const int node = t >> 2, cg = t & 3;
  float acc[10];
#pragma unroll
  for (int c = 0; c < 10; ++c) acc[c] = 0.f;
  for (int k = 0; k < F_H; ++k) {
    float xv = hs[node * 68 + k];
#pragma unroll
    for (int c = 0; c < 10; ++c) acc[c] += xv * w2s[k * NC + cg * 10 + c];
  }
  const int gn = nb + node;
  float ps = 0.f, pd = 0.f;
#pragma unroll
  for (int c = 0; c < 10; ++c) {
    ps += acc[c] * a_src2[cg * 10 + c];
    pd += acc[c] * a_dst2[cg * 10 + c];
  }
  ps += __shfl_xor(ps, 1); ps += __shfl_xor(ps, 2);
  pd += __shfl_xor(pd, 1); pd += __shfl_xor(pd, 2);
  if (gn < N_NODES) {
#pragma unroll
    for (int c = 0; c < 10; ++c) h2b[(size_t)gn * NC + cg * 10 + c] = f2bf(acc[c]);
    if (cg == 0) { als2[gn] = ps; ald2[gn] = pd; }
  }
}

// ---------------------------------------------------------------------------
// Layer-2 aggregation + bias + log_softmax. Wave = 8 nodes x 8 lanes;
// lanes l<5 each carry 8 classes (one dwordx4 bf16 gather). Unroll x4.
// ---------------------------------------------------------------------------
__global__ __launch_bounds__(256) void k_agg2n(
    const int* __restrict__ rowstart, const int* __restrict__ csrc,
    const unsigned short* __restrict__ h2b, const float* __restrict__ als2,
    const float* __restrict__ ald2, const float* __restrict__ b2,
    float* __restrict__ out) {
  const int w = (int)((blockIdx.x * 256 + threadIdx.x) >> 6);
  const int lane = threadIdx.x & 63;
  const int grp = lane >> 3;
  const int l = lane & 7;
  const int n = w * 8 + grp;
  const bool live = (n < N_NODES);
  const int e0 = live ? rowstart[n] : 0;
  const int e1 = live ? rowstart[n + 1] : 0;
  const float aldv = live ? ald2[n] : 0.f;
  const bool act = (l < 5);
  const int fo = act ? l * 8 : 0;

  float den = 0.f;
  float acc[8];
#pragma unroll
  for (int k = 0; k < 8; ++k) acc[k] = 0.f;

  int e = e0;
  for (; e + 4 <= e1; e += 4) {
    int4 sv = *reinterpret_cast<const int4*>(&csrc[e]);
    float a0 = als2[sv.x], a1 = als2[sv.y], a2 = als2[sv.z], a3 = als2[sv.w];
    uint4 u0 = *reinterpret_cast<const uint4*>(&h2b[(size_t)sv.x * NC + fo]);
    uint4 u1 = *reinterpret_cast<const uint4*>(&h2b[(size_t)sv.y * NC + fo]);
    uint4 u2 = *reinterpret_cast<const uint4*>(&h2b[(size_t)sv.z * NC + fo]);
    uint4 u3 = *reinterpret_cast<const uint4*>(&h2b[(size_t)sv.w * NC + fo]);
    float p0 = lrexp(a0 + aldv), p1 = lrexp(a1 + aldv);
    float p2 = lrexp(a2 + aldv), p3 = lrexp(a3 + aldv);
    den += (p0 + p1) + (p2 + p3);
    const unsigned int* q0 = &u0.x;
    const unsigned int* q1 = &u1.x;
    const unsigned int* q2 = &u2.x;
    const unsigned int* q3 = &u3.x;
#pragma unroll
    for (int k = 0; k < 4; ++k) {
      acc[2 * k]     += p0 * bf2f((unsigned short)q0[k]) + p1 * bf2f((unsigned short)q1[k])
                      + p2 * bf2f((unsigned short)q2[k]) + p3 * bf2f((unsigned short)q3[k]);
      acc[2 * k + 1] += p0 * bf2f((unsigned short)(q0[k] >> 16)) + p1 * bf2f((unsigned short)(q1[k] >> 16))
                      + p2 * bf2f((unsigned short)(q2[k] >> 16)) + p3 * bf2f((unsigned short)(q3[k] >> 16));
    }
  }
  for (; e < e1; ++e) {
    int s = csrc[e];
    float a = als2[s];
    uint4 u = *reinterpret_cast<const uint4*>(&h2b[(size_t)s * NC + fo]);
    float p = lrexp(a + aldv);
    den += p;
    const unsigned int* q = &u.x;
#pragma unroll
    for (int k = 0; k < 4; ++k) {
      acc[2 * k]     += p * bf2f((unsigned short)q[k]);
      acc[2 * k + 1] += p * bf2f((unsigned short)(q[k] >> 16));
    }
  }

  float o[8];
  float inv = 1.f / den;
  float mx = -1e30f;
#pragma unroll
  for (int k = 0; k < 8; ++k) {
    o[k] = act ? (acc[k] * inv + b2[fo + k]) : -1e30f;
    mx = fmaxf(mx, o[k]);
  }
  mx = fmaxf(mx, __shfl_xor(mx, 1));
  mx = fmaxf(mx, __shfl_xor(mx, 2));
  mx = fmaxf(mx, __shfl_xor(mx, 4));
  float se = 0.f;
#pragma unroll
  for (int k = 0; k < 8; ++k) se += act ? __expf(o[k] - mx) : 0.f;
  se += __shfl_xor(se, 1);
  se += __shfl_xor(se, 2);
  se += __shfl_xor(se, 4);
  if (live && act) {
    float ls = __logf(se);
    float4 r0, r1;
    r0.x = o[0] - mx - ls; r0.y = o[1] - mx - ls;
    r0.z = o[2] - mx - ls; r0.w = o[3] - mx - ls;
    r1.x = o[4] - mx - ls; r1.y = o[5] - mx - ls;
    r1.z = o[6] - mx - ls; r1.w = o[7] - mx - ls;
    *reinterpret_cast<float4*>(&out[(size_t)n * NC + l * 8]) = r0;
    *reinterpret_cast<float4*>(&out[(size_t)n * NC + l * 8 + 4]) = r1;
  }
}

// ---------------------------------------------------------------------------
extern "C" void kernel_launch(void* const* d_in, const int* in_sizes, int n_in,
                              void* d_out, int out_size, void* d_ws, size_t ws_size,
                              hipStream_t stream) {
  const float* x      = (const float*)d_in[0];
  const int*   ei     = (const int*)d_in[1];
  const float* W1     = (const float*)d_in[2];
  const float* a_src1 = (const float*)d_in[3];
  const float* a_dst1 = (const float*)d_in[4];
  const float* b1     = (const float*)d_in[5];
  const float* W2     = (const float*)d_in[6];
  const float* a_src2 = (const float*)d_in[7];
  const float* a_dst2 = (const float*)d_in[8];
  const float* b2     = (const float*)d_in[9];
  float* out = (float*)d_out;

  char* ws = (char*)d_ws;
  size_t o = 0;
  auto carve = [&](size_t bytes) -> char* {
    char* p = ws + o;
    o = (o + bytes + 255) & ~(size_t)255;
    return p;
  };
  int*   bcnt     = (int*)carve((size_t)NB * 8);   // bcnt + bcur contiguous
  int*   bcur     = bcnt + NB;
  int*   rowstart = (int*)carve((size_t)(N_NODES + 1) * 4);
  unsigned int* inter = (unsigned int*)carve((size_t)E_TOT * 4);
  int*   csrc     = (int*)carve((size_t)(E_TOT + 8) * 4);   // +pad for int4 tail read
  uint4* w1f      = (uint4*)carve((size_t)4096 * 16);
  unsigned short* h1b   = (unsigned short*)carve((size_t)N_NODES * F_H * 2);
  float* als1     = (float*)carve((size_t)N_NODES * HEADS * 4);
  float* ald1     = (float*)carve((size_t)N_NODES * HEADS * 4);
  unsigned short* hactb = (unsigned short*)carve((size_t)N_NODES * F_H * 2);
  unsigned short* h2b   = (unsigned short*)carve((size_t)(N_NODES * NC + 8) * 2);
  float* als2     = (float*)carve((size_t)N_NODES * 4);
  float* ald2     = (float*)carve((size_t)N_NODES * 4);
  (void)ws_size; (void)n_in; (void)in_sizes; (void)out_size;

  hipMemsetAsync(bcnt, 0, (size_t)NB * 8, stream);
  k_hist_pack<<<16 + NBH, 256, 0, stream>>>(ei, W1, w1f, bcnt);
  k_fill_gemm<<<FG_T, 256, 0, stream>>>(ei, bcnt, bcur, inter, x, w1f,
                                        a_src1, a_dst1, h1b, als1, ald1);
  k_cfill<<<NB, 256, 0, stream>>>(inter, bcnt, rowstart, csrc);

  const int aggGrid = (N_NODES + 31) / 32;   // 8 nodes/wave, 4 waves/block
  k_agg1n<<<aggGrid, 256, 0, stream>>>(rowstart, csrc, h1b, als1, ald1, b1, hactb);
  k_l2proj<<<(N_NODES + 63) / 64, 256, 0, stream>>>(hactb, W2, a_src2, a_dst2, h2b, als2, ald2);
  k_agg2n<<<aggGrid, 256, 0, stream>>>(rowstart, csrc, h2b, als2, ald2, b2, out);
}

// Round 17
// 245.913 us; speedup vs baseline: 1.5315x; 1.0022x over previous
//
#include <hip/hip_runtime.h>
#include <hip/hip_bf16.h>
#include <cstdint>
#include <cstddef>

#define N_NODES 100000
#define N_EDGES 1600000
#define E_TOT   (N_EDGES + N_NODES)
#define F_IN    512
#define HEADS   8
#define HID     8
#define F_H     64          // HEADS*HID
#define NC      40
#define NEG     0.2f

#define BSH    8            // bucket = dst >> 8 (256 nodes/bucket)
#define NB     391          // ceil(100000/256)
#define CHUNKH 8192         // edges per bhist block
#define NBH    ((E_TOT + CHUNKH - 1) / CHUNKH)   // 208
#define CHUNKF 4096         // edges per bfill block (16KB LDS staging)
#define NBF    ((E_TOT + CHUNKF - 1) / CHUNKF)   // 416
#define CAP    7168         // k_cfill LDS staging entries (avg seg ~4350)
#define GEMM_G ((N_NODES + 63) / 64)             // 1563 gemm blocks
#define FG_T   (GEMM_G + NBF)                    // 1979 blocks in fat kernel
#define FG_R1  (NBF * 4)                         // 1664: interleave region

typedef __attribute__((ext_vector_type(8))) __bf16 bf16x8;
typedef __attribute__((ext_vector_type(4))) float f32x4;
typedef __attribute__((ext_vector_type(8))) unsigned short u16x8;

__device__ __forceinline__ float bf2f(unsigned short u) {
  unsigned int w = ((unsigned int)u) << 16;
  return __builtin_bit_cast(float, w);
}
__device__ __forceinline__ unsigned short f2bf(float f) {
  __hip_bfloat16 b = __float2bfloat16(f);
  return __builtin_bit_cast(unsigned short, b);
}
__device__ __forceinline__ float lrexp(float v) {
  v = (v > 0.f) ? v : NEG * v;
  return __expf(v);
}

// Per-block edge_index dtype probe: int64 layout -> high int32 words of the
// first 64 entries are all 0. One wave-wide ballot, L2-hot after first block.
__device__ __forceinline__ bool detect_i64(const int* __restrict__ ei) {
  int lane = threadIdx.x & 63;
  int v = ei[2 * lane + 1];
  return __ballot(v != 0) == 0ull;
}

__device__ __forceinline__ int load_dst(const int* __restrict__ ei, bool f, int i) {
  if (i < N_EDGES) return f ? ei[2 * (N_EDGES + i)] : ei[N_EDGES + i];
  return i - N_EDGES;
}
__device__ __forceinline__ int load_src(const int* __restrict__ ei, bool f, int i) {
  if (i < N_EDGES) return f ? ei[2 * i] : ei[i];
  return i - N_EDGES;
}

// ---------------------------------------------------------------------------
// Fat kernel A: blocks [0,16) pack W1 -> bf16 B-fragment-major; blocks
// [16,16+NBH) histogram dst buckets (LDS-binned).
// ---------------------------------------------------------------------------
__global__ __launch_bounds__(256) void k_hist_pack(
    const int* __restrict__ ei, const float* __restrict__ W1,
    uint4* __restrict__ w1f, int* __restrict__ bcnt) {
  __shared__ int h[NB];
  const int t = threadIdx.x;
  if (blockIdx.x < 16) {
    int tid = blockIdx.x * 256 + t;   // 0..4095
    int lane = tid & 63;
    int tt = (tid >> 6) & 3;
    int s = tid >> 8;
    int k0 = s * 32 + ((lane >> 4) << 3);
    int col = tt * 16 + (lane & 15);
    u16x8 v;
#pragma unroll
    for (int i = 0; i < 8; ++i) v[i] = f2bf(W1[(size_t)(k0 + i) * F_H + col]);
    w1f[tid] = __builtin_bit_cast(uint4, v);
    return;
  }
  const int blk = blockIdx.x - 16;
  const bool f = detect_i64(ei);
  for (int i = t; i < NB; i += 256) h[i] = 0;
  __syncthreads();
  const int base = blk * CHUNKH;
#pragma unroll
  for (int j = 0; j < CHUNKH / 256; ++j) {
    int i = base + t + j * 256;
    if (i < E_TOT) atomicAdd(&h[load_dst(ei, f, i) >> BSH], 1);
  }
  __syncthreads();
  for (int i = t; i < NB; i += 256)
    if (h[i]) atomicAdd(&bcnt[i], h[i]);
}

// ---------------------------------------------------------------------------
// Fat kernel B: gemm1m blocks interleaved with bfill blocks (every 4th block
// in the first FG_R1 blocks is bfill). bfill computes the bucket prefix scan
// LOCALLY from bcnt; bcur is zero-seeded, global position = bst + atomicAdd.
// GEMM: nt x loads + bijective XCD-chunked idx swizzle (T1/m204) so each XCD
// reads one contiguous ~25MB slab of x (locality on the L3-read fabric).
// ---------------------------------------------------------------------------
__global__ __launch_bounds__(256) void k_fill_gemm(
    const int* __restrict__ ei, const int* __restrict__ bcnt,
    int* __restrict__ bcur, unsigned int* __restrict__ inter,
    const float* __restrict__ x, const uint4* __restrict__ w1f,
    const float* __restrict__ a_src, const float* __restrict__ a_dst,
    unsigned short* __restrict__ h1b, float* __restrict__ als,
    float* __restrict__ ald) {
  __shared__ unsigned int ent[CHUNKF];                       // 16 KB
  __shared__ int h[NB], ofs[NB], cur[NB], gpos[NB], bst[NB]; // ~7.8 KB
  const int b = (int)blockIdx.x;
  const int t = threadIdx.x;
  bool isFill;
  int idx;
  if (b < FG_R1) {
    if ((b & 3) == 3) { isFill = true;  idx = b >> 2; }
    else              { isFill = false; idx = b - (b >> 2); }
  } else {
    isFill = false; idx = b - NBF;
  }

  if (isFill) {
    // ---- bfill(idx) ----
    const bool f = detect_i64(ei);
    const int base = idx * CHUNKF;
    for (int i = t; i < NB; i += 256) h[i] = 0;
    __syncthreads();
#pragma unroll
    for (int j = 0; j < CHUNKF / 256; ++j) {
      int i = base + t + j * 256;
      if (i < E_TOT) atomicAdd(&h[load_dst(ei, f, i) >> BSH], 1);
    }
    __syncthreads();
    if (t < 64) {
      // local scan of per-block histogram h -> ofs
      int loc[7];
      int s = 0;
#pragma unroll
      for (int k = 0; k < 7; ++k) {
        int ix = t * 7 + k;
        int hv = (ix < NB) ? h[ix] : 0;
        loc[k] = s;
        s += hv;
      }
      int incl = s;
      for (int dd = 1; dd < 64; dd <<= 1) {
        int u = __shfl_up(incl, dd);
        if (t >= dd) incl += u;
      }
      int excl = incl - s;
#pragma unroll
      for (int k = 0; k < 7; ++k) {
        int ix = t * 7 + k;
        if (ix < NB) ofs[ix] = excl + loc[k];
      }
    } else if (t < 128) {
      // local scan of GLOBAL bucket counts bcnt -> bst (wave 1)
      int tl = t - 64;
      int loc[7];
      int s = 0;
#pragma unroll
      for (int k = 0; k < 7; ++k) {
        int ix = tl * 7 + k;
        int hv = (ix < NB) ? bcnt[ix] : 0;
        loc[k] = s;
        s += hv;
      }
      int incl = s;
      for (int dd = 1; dd < 64; dd <<= 1) {
        int u = __shfl_up(incl, dd);
        if (tl >= dd) incl += u;
      }
      int excl = incl - s;
#pragma unroll
      for (int k = 0; k < 7; ++k) {
        int ix = tl * 7 + k;
        if (ix < NB) bst[ix] = excl + loc[k];
      }
    }
    __syncthreads();
    for (int i = t; i < NB; i += 256) {
      cur[i] = ofs[i];
      gpos[i] = h[i] ? (bst[i] + atomicAdd(&bcur[i], h[i])) : 0;
    }
    __syncthreads();
#pragma unroll
    for (int j = 0; j < CHUNKF / 256; ++j) {
      int i = base + t + j * 256;
      if (i < E_TOT) {
        int s = load_src(ei, f, i);
        int d = load_dst(ei, f, i);
        int p = atomicAdd(&cur[d >> BSH], 1);
        ent[p] = ((unsigned int)(d & 255) << 24) | (unsigned int)s;
      }
    }
    __syncthreads();
    const int wv = t >> 6, ln = t & 63;
    for (int bb = wv; bb < NB; bb += 4) {
      int c = h[bb];
      if (!c) continue;
      int g = gpos[bb], o = ofs[bb];
      for (int i = ln; i < c; i += 64) inter[g + i] = ent[o + i];
    }
    return;
  }

  // ---- gemm1m: bijective XCD-chunked remap of idx (q=GEMM_G/8, r=GEMM_G%8)
  {
    const int q = GEMM_G >> 3, r = GEMM_G & 7;
    int xc = idx & 7, pos = idx >> 3;
    idx = (xc < r) ? (xc * (q + 1) + pos) : (r * (q + 1) + (xc - r) * q + pos);
  }
  const int lane = t & 63;
  const int wv = t >> 6;
  const int rb = idx * 64 + wv * 16;
  int arow = rb + (lane & 15);
  if (arow >= N_NODES) arow = N_NODES - 1;   // clamp; stores predicated
  const float* aptr = x + (size_t)arow * F_IN + ((lane >> 4) << 3);

  f32x4 acc[4];
#pragma unroll
  for (int i = 0; i < 4; ++i) acc[i] = (f32x4){0.f, 0.f, 0.f, 0.f};

#pragma unroll 4
  for (int s = 0; s < 16; ++s) {
    f32x4 a0 = __builtin_nontemporal_load(
        reinterpret_cast<const f32x4*>(aptr + s * 32));
    f32x4 a1 = __builtin_nontemporal_load(
        reinterpret_cast<const f32x4*>(aptr + s * 32 + 4));
    uint4 b0 = w1f[(s * 4 + 0) * 64 + lane];
    uint4 b1 = w1f[(s * 4 + 1) * 64 + lane];
    uint4 b2 = w1f[(s * 4 + 2) * 64 + lane];
    uint4 b3 = w1f[(s * 4 + 3) * 64 + lane];
    bf16x8 af;
    af[0] = (__bf16)a0[0]; af[1] = (__bf16)a0[1];
    af[2] = (__bf16)a0[2]; af[3] = (__bf16)a0[3];
    af[4] = (__bf16)a1[0]; af[5] = (__bf16)a1[1];
    af[6] = (__bf16)a1[2]; af[7] = (__bf16)a1[3];
    acc[0] = __builtin_amdgcn_mfma_f32_16x16x32_bf16(af, __builtin_bit_cast(bf16x8, b0), acc[0], 0, 0, 0);
    acc[1] = __builtin_amdgcn_mfma_f32_16x16x32_bf16(af, __builtin_bit_cast(bf16x8, b1), acc[1], 0, 0, 0);
    acc[2] = __builtin_amdgcn_mfma_f32_16x16x32_bf16(af, __builtin_bit_cast(bf16x8, b2), acc[2], 0, 0, 0);
    acc[3] = __builtin_amdgcn_mfma_f32_16x16x32_bf16(af, __builtin_bit_cast(bf16x8, b3), acc[3], 0, 0, 0);
  }

  const int r0 = rb + ((lane >> 4) << 2);
  const int c = lane & 15;
#pragma unroll
  for (int tt = 0; tt < 4; ++tt) {
#pragma unroll
    for (int i = 0; i < 4; ++i) {
      int r = r0 + i;
      if (r < N_NODES) h1b[(size_t)r * F_H + tt * 16 + c] = f2bf(acc[tt][i]);
    }
  }

  float asw[4], adw[4];
#pragma unroll
  for (int tt = 0; tt < 4; ++tt) {
    asw[tt] = a_src[tt * 16 + c];
    adw[tt] = a_dst[tt * 16 + c];
  }
  float sp[4][4], dp[4][4];
#pragma unroll
  for (int tt = 0; tt < 4; ++tt)
#pragma unroll
    for (int i = 0; i < 4; ++i) {
      sp[tt][i] = acc[tt][i] * asw[tt];
      dp[tt][i] = acc[tt][i] * adw[tt];
    }
#pragma unroll
  for (int dd = 1; dd < 8; dd <<= 1)
#pragma unroll
    for (int tt = 0; tt < 4; ++tt)
#pragma unroll
      for (int i = 0; i < 4; ++i) {
        sp[tt][i] += __shfl_xor(sp[tt][i], dd);
        dp[tt][i] += __shfl_xor(dp[tt][i], dd);
      }
  if ((c & 7) == 0) {
    const int hb = c >> 3;
#pragma unroll
    for (int i = 0; i < 4; ++i) {
      int r = r0 + i;
      if (r < N_NODES) {
#pragma unroll
        for (int tt = 0; tt < 4; ++tt) {
          als[(size_t)r * HEADS + tt * 2 + hb] = sp[tt][i];
          ald[(size_t)r * HEADS + tt * 2 + hb] = dp[tt][i];
        }
      }
    }
  }
}

// ---------------------------------------------------------------------------
// One block per bucket; LDS counting sort -> csrc + rowstart coalesced.
// segStart computed locally: block-reduce prefix of bcnt[0..b); L = bcnt[b].
// ---------------------------------------------------------------------------
__global__ __launch_bounds__(256) void k_cfill(const unsigned int* __restrict__ inter,
                                               const int* __restrict__ bcnt,
                                               int* __restrict__ rowstart,
                                               int* __restrict__ csrc) {
  __shared__ unsigned int out_l[CAP];      // 28 KB
  __shared__ int cnt[256], sc[256], cur2[256], red[256];
  const int t = threadIdx.x;
  const int b = blockIdx.x;

  int partial = 0;
  for (int i = t; i < b; i += 256) partial += bcnt[i];
  red[t] = partial;
  cnt[t] = 0;
  __syncthreads();
  for (int d = 128; d > 0; d >>= 1) {
    if (t < d) red[t] += red[t + d];
    __syncthreads();
  }
  const int segStart = red[0];
  const int L = bcnt[b];
  if (b == 0 && t == 0) rowstart[N_NODES] = E_TOT;

  for (int i = t; i < L; i += 256) atomicAdd(&cnt[inter[segStart + i] >> 24], 1);
  __syncthreads();
  sc[t] = cnt[t];
  __syncthreads();
  for (int d = 1; d < 256; d <<= 1) {
    int v = (t >= d) ? sc[t - d] : 0;
    __syncthreads();
    sc[t] += v;
    __syncthreads();
  }
  const int excl = sc[t] - cnt[t];
  cur2[t] = excl;
  const int node = (b << BSH) + t;
  if (node < N_NODES) rowstart[node] = segStart + excl;
  __syncthreads();
  if (L <= CAP) {
    for (int i = t; i < L; i += 256) {
      unsigned int e = inter[segStart + i];
      int p = atomicAdd(&cur2[e >> 24], 1);
      out_l[p] = e & 0xFFFFFFu;
    }
    __syncthreads();
    for (int i = t; i < L; i += 256) csrc[segStart + i] = (int)out_l[i];
  } else {  // safety fallback (statistically never taken)
    for (int i = t; i < L; i += 256) {
      unsigned int e = inter[segStart + i];
      int p = atomicAdd(&cur2[e >> 24], 1);
      csrc[segStart + p] = (int)(e & 0xFFFFFFu);
    }
  }
}

// ---------------------------------------------------------------------------
// Layer-1 aggregation: wave = 8 nodes x 8 lanes. Lane = head = 8 features
// (one dwordx4 of bf16 per edge). Unroll x4 -> 32 gathers in flight per wave.
// ---------------------------------------------------------------------------
__global__ __launch_bounds__(256) void k_agg1n(
    const int* __restrict__ rowstart, const int* __restrict__ csrc,
    const unsigned short* __restrict__ h1b, const float* __restrict__ als,
    const float* __restrict__ ald, const float* __restrict__ b1,
    unsigned short* __restrict__ hactb) {
  const int w = (int)((blockIdx.x * 256 + threadIdx.x) >> 6);
  const int lane = threadIdx.x & 63;
  const int grp = lane >> 3;        // node slot 0..7
  const int l = lane & 7;           // head / feature octet
  const int n = w * 8 + grp;
  const bool live = (n < N_NODES);
  const int e0 = live ? rowstart[n] : 0;
  const int e1 = live ? rowstart[n + 1] : 0;
  const float aldv = live ? ald[(size_t)n * HEADS + l] : 0.f;

  float den = 0.f;
  float acc[8];
#pragma unroll
  for (int k = 0; k < 8; ++k) acc[k] = 0.f;

  int e = e0;
  for (; e + 4 <= e1; e += 4) {
    int4 sv = *reinterpret_cast<const int4*>(&csrc[e]);
    float a0 = als[(size_t)sv.x * HEADS + l];
    float a1 = als[(size_t)sv.y * HEADS + l];
    float a2 = als[(size_t)sv.z * HEADS + l];
    float a3 = als[(size_t)sv.w * HEADS + l];
    uint4 u0 = *reinterpret_cast<const uint4*>(&h1b[(size_t)sv.x * F_H + l * 8]);
    uint4 u1 = *reinterpret_cast<const uint4*>(&h1b[(size_t)sv.y * F_H + l * 8]);
    uint4 u2 = *reinterpret_cast<const uint4*>(&h1b[(size_t)sv.z * F_H + l * 8]);
    uint4 u3 = *reinterpret_cast<const uint4*>(&h1b[(size_t)sv.w * F_H + l * 8]);
    float p0 = lrexp(a0 + aldv), p1 = lrexp(a1 + aldv);
    float p2 = lrexp(a2 + aldv), p3 = lrexp(a3 + aldv);
    den += (p0 + p1) + (p2 + p3);
    const unsigned int* q0 = &u0.x;
    const unsigned int* q1 = &u1.x;
    const unsigned int* q2 = &u2.x;
    const unsigned int* q3 = &u3.x;
#pragma unroll
    for (int k = 0; k < 4; ++k) {
      acc[2 * k]     += p0 * bf2f((unsigned short)q0[k]) + p1 * bf2f((unsigned short)q1[k])
                      + p2 * bf2f((unsigned short)q2[k]) + p3 * bf2f((unsigned short)q3[k]);
      acc[2 * k + 1] += p0 * bf2f((unsigned short)(q0[k] >> 16)) + p1 * bf2f((unsigned short)(q1[k] >> 16))
                      + p2 * bf2f((unsigned short)(q2[k] >> 16)) + p3 * bf2f((unsigned short)(q3[k] >> 16));
    }
  }
  for (; e < e1; ++e) {
    int s = csrc[e];
    float a = als[(size_t)s * HEADS + l];
    uint4 u = *reinterpret_cast<const uint4*>(&h1b[(size_t)s * F_H + l * 8]);
    float p = lrexp(a + aldv);
    den += p;
    const unsigned int* q = &u.x;
#pragma unroll
    for (int k = 0; k < 4; ++k) {
      acc[2 * k]     += p * bf2f((unsigned short)q[k]);
      acc[2 * k + 1] += p * bf2f((unsigned short)(q[k] >> 16));
    }
  }

  if (live) {
    float inv = 1.f / den;
    uint4 outw;
    unsigned int* ow = &outw.x;
#pragma unroll
    for (int k = 0; k < 4; ++k) {
      float ox = acc[2 * k] * inv + b1[l * 8 + 2 * k];
      float oy = acc[2 * k + 1] * inv + b1[l * 8 + 2 * k + 1];
      ox = (ox > 0.f) ? ox : expm1f(ox);
      oy = (oy > 0.f) ? oy : expm1f(oy);
      ow[k] = ((unsigned int)f2bf(oy) << 16) | (unsigned int)f2bf(ox);
    }
    *reinterpret_cast<uint4*>(&hactb[(size_t)n * F_H + l * 8]) = outw;
  }
}

// ---------------------------------------------------------------------------
// Layer-2 projection: h2 = hact @ W2 (64x40) + attention logits (1 head).
// ---------------------------------------------------------------------------
__global__ __launch_bounds__(256) void k_l2proj(
    const unsigned short* __restrict__ hactb, const float* __restrict__ W2,
    const float* __restrict__ a_src2, const float* __restrict__ a_dst2,
    unsigned short* __restrict__ h2b, float* __restrict__ als2,
    float* __restrict__ ald2) {
  __shared__ float hs[64 * 68];
  __shared__ float w2s[F_H * NC];
  const int t = threadIdx.x;
  const int nb = blockIdx.x * 64;
  {
    int r0 = t >> 3, c8 = t & 7;
#pragma unroll
    for (int i = 0; i < 2; ++i) {
      int r = r0 + i * 32;
      int gr = nb + r;
      u16x8 v = (u16x8)(0);
      if (gr < N_NODES)
        v = *reinterpret_cast<const u16x8*>(&hactb[(size_t)gr * F_H + c8 * 8]);
#pragma unroll
      for (int k = 0; k < 8; ++k) hs[r * 68 + c8 * 8 + k] = bf2f(v[k]);
    }
  }
  for (int i = t; i < F_H * NC; i += 256) w2s[i] = W2[i];
  __syncthreads();

  const int node = t >> 2, cg = t & 3;
  float acc[10];
#pragma unroll
  for (int c = 0; c < 10; ++c) acc[c] = 0.f;
  for (int k = 0; k < F_H; ++k) {
    float xv = hs[node * 68 + k];
#pragma unroll
    for (int c = 0; c < 10; ++c) acc[c] += xv * w2s[k * NC + cg * 10 + c];
  }
  const int gn = nb + node;
  float ps = 0.f, pd = 0.f;
#pragma unroll
  for (int c = 0; c < 10; ++c) {
    ps += acc[c] * a_src2[cg * 10 + c];
    pd += acc[c] * a_dst2[cg * 10 + c];
  }
  ps += __shfl_xor(ps, 1); ps += __shfl_xor(ps, 2);
  pd += __shfl_xor(pd, 1); pd += __shfl_xor(pd, 2);
  if (gn < N_NODES) {
#pragma unroll
    for (int c = 0; c < 10; ++c) h2b[(size_t)gn * NC + cg * 10 + c] = f2bf(acc[c]);
    if (cg == 0) { als2[gn] = ps; ald2[gn] = pd; }
  }
}

// ---------------------------------------------------------------------------
// Layer-2 aggregation + bias + log_softmax. Wave = 8 nodes x 8 lanes;
// lanes l<5 each carry 8 classes (one dwordx4 bf16 gather). Unroll x4.
// ---------------------------------------------------------------------------
__global__ __launch_bounds__(256) void k_agg2n(
    const int* __restrict__ rowstart, const int* __restrict__ csrc,
    const unsigned short* __restrict__ h2b, const float* __restrict__ als2,
    const float* __restrict__ ald2, const float* __restrict__ b2,
    float* __restrict__ out) {
  const int w = (int)((blockIdx.x * 256 + threadIdx.x) >> 6);
  const int lane = threadIdx.x & 63;
  const int grp = lane >> 3;
  const int l = lane & 7;
  const int n = w * 8 + grp;
  const bool live = (n < N_NODES);
  const int e0 = live ? rowstart[n] : 0;
  const int e1 = live ? rowstart[n + 1] : 0;
  const float aldv = live ? ald2[n] : 0.f;
  const bool act = (l < 5);
  const int fo = act ? l * 8 : 0;

  float den = 0.f;
  float acc[8];
#pragma unroll
  for (int k = 0; k < 8; ++k) acc[k] = 0.f;

  int e = e0;
  for (; e + 4 <= e1; e += 4) {
    int4 sv = *reinterpret_cast<const int4*>(&csrc[e]);
    float a0 = als2[sv.x], a1 = als2[sv.y], a2 = als2[sv.z], a3 = als2[sv.w];
    uint4 u0 = *reinterpret_cast<const uint4*>(&h2b[(size_t)sv.x * NC + fo]);
    uint4 u1 = *reinterpret_cast<const uint4*>(&h2b[(size_t)sv.y * NC + fo]);
    uint4 u2 = *reinterpret_cast<const uint4*>(&h2b[(size_t)sv.z * NC + fo]);
    uint4 u3 = *reinterpret_cast<const uint4*>(&h2b[(size_t)sv.w * NC + fo]);
    float p0 = lrexp(a0 + aldv), p1 = lrexp(a1 + aldv);
    float p2 = lrexp(a2 + aldv), p3 = lrexp(a3 + aldv);
    den += (p0 + p1) + (p2 + p3);
    const unsigned int* q0 = &u0.x;
    const unsigned int* q1 = &u1.x;
    const unsigned int* q2 = &u2.x;
    const unsigned int* q3 = &u3.x;
#pragma unroll
    for (int k = 0; k < 4; ++k) {
      acc[2 * k]     += p0 * bf2f((unsigned short)q0[k]) + p1 * bf2f((unsigned short)q1[k])
                      + p2 * bf2f((unsigned short)q2[k]) + p3 * bf2f((unsigned short)q3[k]);
      acc[2 * k + 1] += p0 * bf2f((unsigned short)(q0[k] >> 16)) + p1 * bf2f((unsigned short)(q1[k] >> 16))
                      + p2 * bf2f((unsigned short)(q2[k] >> 16)) + p3 * bf2f((unsigned short)(q3[k] >> 16));
    }
  }
  for (; e < e1; ++e) {
    int s = csrc[e];
    float a = als2[s];
    uint4 u = *reinterpret_cast<const uint4*>(&h2b[(size_t)s * NC + fo]);
    float p = lrexp(a + aldv);
    den += p;
    const unsigned int* q = &u.x;
#pragma unroll
    for (int k = 0; k < 4; ++k) {
      acc[2 * k]     += p * bf2f((unsigned short)q[k]);
      acc[2 * k + 1] += p * bf2f((unsigned short)(q[k] >> 16));
    }
  }

  float o[8];
  float inv = 1.f / den;
  float mx = -1e30f;
#pragma unroll
  for (int k = 0; k < 8; ++k) {
    o[k] = act ? (acc[k] * inv + b2[fo + k]) : -1e30f;
    mx = fmaxf(mx, o[k]);
  }
  mx = fmaxf(mx, __shfl_xor(mx, 1));
  mx = fmaxf(mx, __shfl_xor(mx, 2));
  mx = fmaxf(mx, __shfl_xor(mx, 4));
  float se = 0.f;
#pragma unroll
  for (int k = 0; k < 8; ++k) se += act ? __expf(o[k] - mx) : 0.f;
  se += __shfl_xor(se, 1);
  se += __shfl_xor(se, 2);
  se += __shfl_xor(se, 4);
  if (live && act) {
    float ls = __logf(se);
    float4 r0, r1;
    r0.x = o[0] - mx - ls; r0.y = o[1] - mx - ls;
    r0.z = o[2] - mx - ls; r0.w = o[3] - mx - ls;
    r1.x = o[4] - mx - ls; r1.y = o[5] - mx - ls;
    r1.z = o[6] - mx - ls; r1.w = o[7] - mx - ls;
    *reinterpret_cast<float4*>(&out[(size_t)n * NC + l * 8]) = r0;
    *reinterpret_cast<float4*>(&out[(size_t)n * NC + l * 8 + 4]) = r1;
  }
}

// ---------------------------------------------------------------------------
extern "C" void kernel_launch(void* const* d_in, const int* in_sizes, int n_in,
                              void* d_out, int out_size, void* d_ws, size_t ws_size,
                              hipStream_t stream) {
  const float* x      = (const float*)d_in[0];
  const int*   ei     = (const int*)d_in[1];
  const float* W1     = (const float*)d_in[2];
  const float* a_src1 = (const float*)d_in[3];
  const float* a_dst1 = (const float*)d_in[4];
  const float* b1     = (const float*)d_in[5];
  const float* W2     = (const float*)d_in[6];
  const float* a_src2 = (const float*)d_in[7];
  const float* a_dst2 = (const float*)d_in[8];
  const float* b2     = (const float*)d_in[9];
  float* out = (float*)d_out;

  char* ws = (char*)d_ws;
  size_t o = 0;
  auto carve = [&](size_t bytes) -> char* {
    char* p = ws + o;
    o = (o + bytes + 255) & ~(size_t)255;
    return p;
  };
  int*   bcnt     = (int*)carve((size_t)NB * 8);   // bcnt + bcur contiguous
  int*   bcur     = bcnt + NB;
  int*   rowstart = (int*)carve((size_t)(N_NODES + 1) * 4);
  unsigned int* inter = (unsigned int*)carve((size_t)E_TOT * 4);
  int*   csrc     = (int*)carve((size_t)(E_TOT + 8) * 4);   // +pad for int4 tail read
  uint4* w1f      = (uint4*)carve((size_t)4096 * 16);
  unsigned short* h1b   = (unsigned short*)carve((size_t)N_NODES * F_H * 2);
  float* als1     = (float*)carve((size_t)N_NODES * HEADS * 4);
  float* ald1     = (float*)carve((size_t)N_NODES * HEADS * 4);
  unsigned short* hactb = (unsigned short*)carve((size_t)N_NODES * F_H * 2);
  unsigned short* h2b   = (unsigned short*)carve((size_t)(N_NODES * NC + 8) * 2);
  float* als2     = (float*)carve((size_t)N_NODES * 4);
  float* ald2     = (float*)carve((size_t)N_NODES * 4);
  (void)ws_size; (void)n_in; (void)in_sizes; (void)out_size;

  hipMemsetAsync(bcnt, 0, (size_t)NB * 8, stream);
  k_hist_pack<<<16 + NBH, 256, 0, stream>>>(ei, W1, w1f, bcnt);
  k_fill_gemm<<<FG_T, 256, 0, stream>>>(ei, bcnt, bcur, inter, x, w1f,
                                        a_src1, a_dst1, h1b, als1, ald1);
  k_cfill<<<NB, 256, 0, stream>>>(inter, bcnt, rowstart, csrc);

  const int aggGrid = (N_NODES + 31) / 32;   // 8 nodes/wave, 4 waves/block
  k_agg1n<<<aggGrid, 256, 0, stream>>>(rowstart, csrc, h1b, als1, ald1, b1, hactb);
  k_l2proj<<<(N_NODES + 63) / 64, 256, 0, stream>>>(hactb, W2, a_src2, a_dst2, h2b, als2, ald2);
  k_agg2n<<<aggGrid, 256, 0, stream>>>(rowstart, csrc, h2b, als2, ald2, b2, out);
}